// Round 1
// baseline (5664.200 us; speedup 1.0000x reference)
//
#include <hip/hip_runtime.h>
#include <hip/hip_bf16.h>
#include <cstdint>
#include <cstddef>

#define D_IN    32
#define D_MAIN  256
#define D_BLOCK 512
#define CTX     96
#define NQ      1024
#define NTRAIN  100000

// ---------------------------------------------------------------------------
// Generic fp32 GEMM: C[M,N] = act( alpha*(A[M,K] @ B[N,K]^T) + biasScale*bias[n] + resid[m,n] )
// 64x64 block tile, 16 K-step, 256 threads, 4x4 microtile.
// ---------------------------------------------------------------------------
#define TILE 64
#define KT   16

__global__ __launch_bounds__(256) void gemm_bias_act(
    const float* __restrict__ A, const float* __restrict__ B,
    const float* __restrict__ bias, float biasScale,
    const float* __restrict__ resid,
    float* __restrict__ C,
    int M, int N, int K, float alpha, int relu)
{
    __shared__ float As[KT][TILE + 4];
    __shared__ float Bs[KT][TILE + 4];
    const int bm = blockIdx.y * TILE;
    const int bn = blockIdx.x * TILE;
    const int tid = threadIdx.x;
    const int tx = tid & 15;        // n direction
    const int ty = tid >> 4;        // m direction
    const int lm = tid >> 2;        // 0..63 row within tile for loads
    const int lk = (tid & 3) * 4;   // 0,4,8,12 k-quad

    float acc[4][4];
#pragma unroll
    for (int i = 0; i < 4; ++i)
#pragma unroll
        for (int j = 0; j < 4; ++j) acc[i][j] = 0.f;

    for (int k0 = 0; k0 < K; k0 += KT) {
        {
            const int gm = bm + lm;
            float4 v = make_float4(0.f, 0.f, 0.f, 0.f);
            if (gm < M) v = *reinterpret_cast<const float4*>(A + (size_t)gm * K + k0 + lk);
            As[lk + 0][lm] = v.x; As[lk + 1][lm] = v.y;
            As[lk + 2][lm] = v.z; As[lk + 3][lm] = v.w;
            const int gn = bn + lm;
            float4 w = make_float4(0.f, 0.f, 0.f, 0.f);
            if (gn < N) w = *reinterpret_cast<const float4*>(B + (size_t)gn * K + k0 + lk);
            Bs[lk + 0][lm] = w.x; Bs[lk + 1][lm] = w.y;
            Bs[lk + 2][lm] = w.z; Bs[lk + 3][lm] = w.w;
        }
        __syncthreads();
#pragma unroll
        for (int kk = 0; kk < KT; ++kk) {
            float aa[4], bb[4];
#pragma unroll
            for (int i = 0; i < 4; ++i) aa[i] = As[kk][ty * 4 + i];
#pragma unroll
            for (int j = 0; j < 4; ++j) bb[j] = Bs[kk][tx * 4 + j];
#pragma unroll
            for (int i = 0; i < 4; ++i)
#pragma unroll
                for (int j = 0; j < 4; ++j) acc[i][j] += aa[i] * bb[j];
        }
        __syncthreads();
    }

#pragma unroll
    for (int i = 0; i < 4; ++i) {
        const int gm = bm + ty * 4 + i;
        if (gm >= M) continue;
#pragma unroll
        for (int j = 0; j < 4; ++j) {
            const int gn = bn + tx * 4 + j;
            if (gn >= N) continue;
            float v = alpha * acc[i][j];
            if (bias)  v += biasScale * bias[gn];
            if (resid) v += resid[(size_t)gm * N + gn];
            if (relu)  v = fmaxf(v, 0.f);
            C[(size_t)gm * N + gn] = v;
        }
    }
}

// ---------------------------------------------------------------------------
// Row LayerNorm (D=256): one wave64 per row, 4 rows per 256-thread block.
// ---------------------------------------------------------------------------
__global__ void ln_kernel(const float* __restrict__ X, const float* __restrict__ g,
                          const float* __restrict__ b, float* __restrict__ Y, int M)
{
    const int row = blockIdx.x * 4 + (threadIdx.x >> 6);
    const int lane = threadIdx.x & 63;
    if (row >= M) return;
    const float* x = X + (size_t)row * D_MAIN;
    float v[4];
    float s = 0.f;
#pragma unroll
    for (int i = 0; i < 4; ++i) { v[i] = x[lane + 64 * i]; s += v[i]; }
#pragma unroll
    for (int o = 32; o > 0; o >>= 1) s += __shfl_xor(s, o);
    const float mu = s * (1.f / D_MAIN);
    float vs = 0.f;
#pragma unroll
    for (int i = 0; i < 4; ++i) { const float d = v[i] - mu; vs += d * d; }
#pragma unroll
    for (int o = 32; o > 0; o >>= 1) vs += __shfl_xor(vs, o);
    const float inv = rsqrtf(vs * (1.f / D_MAIN) + 1e-5f);
    float* y = Y + (size_t)row * D_MAIN;
#pragma unroll
    for (int i = 0; i < 4; ++i) {
        const int d = lane + 64 * i;
        y[d] = (v[i] - mu) * inv * g[d] + b[d];
    }
}

// sq[row] = sum_d X[row][d]^2
__global__ void rowsq_kernel(const float* __restrict__ X, float* __restrict__ sq, int M)
{
    const int row = blockIdx.x * 4 + (threadIdx.x >> 6);
    const int lane = threadIdx.x & 63;
    if (row >= M) return;
    const float* x = X + (size_t)row * D_MAIN;
    float s = 0.f;
#pragma unroll
    for (int i = 0; i < 4; ++i) { const float v = x[lane + 64 * i]; s += v * v; }
#pragma unroll
    for (int o = 32; o > 0; o >>= 1) s += __shfl_xor(s, o);
    if (lane == 0) sq[row] = s;
}

// out[row] = relu(LN(x,g,b)) . W + bh
__global__ void head_kernel(const float* __restrict__ X, const float* __restrict__ g,
                            const float* __restrict__ b, const float* __restrict__ W,
                            const float* __restrict__ bh, float* __restrict__ out, int M)
{
    const int row = blockIdx.x * 4 + (threadIdx.x >> 6);
    const int lane = threadIdx.x & 63;
    if (row >= M) return;
    const float* x = X + (size_t)row * D_MAIN;
    float v[4];
    float s = 0.f;
#pragma unroll
    for (int i = 0; i < 4; ++i) { v[i] = x[lane + 64 * i]; s += v[i]; }
#pragma unroll
    for (int o = 32; o > 0; o >>= 1) s += __shfl_xor(s, o);
    const float mu = s * (1.f / D_MAIN);
    float vs = 0.f;
#pragma unroll
    for (int i = 0; i < 4; ++i) { const float d = v[i] - mu; vs += d * d; }
#pragma unroll
    for (int o = 32; o > 0; o >>= 1) vs += __shfl_xor(vs, o);
    const float inv = rsqrtf(vs * (1.f / D_MAIN) + 1e-5f);
    float acc = 0.f;
#pragma unroll
    for (int i = 0; i < 4; ++i) {
        const int d = lane + 64 * i;
        float o_ = (v[i] - mu) * inv * g[d] + b[d];
        o_ = fmaxf(o_, 0.f);
        acc += o_ * W[d];
    }
#pragma unroll
    for (int o = 32; o > 0; o >>= 1) acc += __shfl_xor(acc, o);
    if (lane == 0) out[row] = acc + bh[0];
}

// ---------------------------------------------------------------------------
// Top-96 per score row via 4-pass radix select on float-ordered keys.
// Deterministic: gathered (idx,val) sorted by index ascending.
// ---------------------------------------------------------------------------
__global__ __launch_bounds__(256) void topk_kernel(
    const float* __restrict__ scores, int N, int q0,
    int* __restrict__ idxA, float* __restrict__ sscA)
{
    const int qloc = blockIdx.x;
    const int q = q0 + qloc;
    const float* row = scores + (size_t)qloc * N;
    const int tid = threadIdx.x;
    __shared__ unsigned hist[256];
    __shared__ unsigned sh_prefix;
    __shared__ int sh_k;
    unsigned prefix = 0;
    int kneed = CTX;

    for (int pass = 0; pass < 4; ++pass) {
        hist[tid] = 0;
        __syncthreads();
        const int shift = 24 - 8 * pass;
        for (int n = tid; n < N; n += 256) {
            const unsigned u = __float_as_uint(row[n]);
            const unsigned key = (u & 0x80000000u) ? ~u : (u | 0x80000000u);
            const bool ok = (pass == 0) || ((key >> (shift + 8)) == prefix);
            if (ok) atomicAdd(&hist[(key >> shift) & 0xFFu], 1u);
        }
        __syncthreads();
        if (tid == 0) {
            unsigned cum = 0;
            int chosen = 0;
            for (int bn = 255; bn >= 0; --bn) {
                const unsigned c = hist[bn];
                if (cum + c >= (unsigned)kneed) { chosen = bn; break; }
                cum += c;
            }
            sh_prefix = (prefix << 8) | (unsigned)chosen;
            sh_k = kneed - (int)cum;
        }
        __syncthreads();
        prefix = sh_prefix;
        kneed = sh_k;
        __syncthreads();
    }

    __shared__ int cntG, cntE;
    __shared__ int gI[CTX];
    __shared__ float gV[CTX];
    __shared__ int eI[128];
    __shared__ float eV[128];
    if (tid == 0) { cntG = 0; cntE = 0; }
    __syncthreads();
    for (int n = tid; n < N; n += 256) {
        const float f = row[n];
        const unsigned u = __float_as_uint(f);
        const unsigned key = (u & 0x80000000u) ? ~u : (u | 0x80000000u);
        if (key > prefix) {
            const int s = atomicAdd(&cntG, 1);
            if (s < CTX) { gI[s] = n; gV[s] = f; }
        } else if (key == prefix) {
            const int s = atomicAdd(&cntE, 1);
            if (s < 128) { eI[s] = n; eV[s] = f; }
        }
    }
    __syncthreads();
    if (tid == 0) {
        int m = cntG; if (m > CTX) m = CTX;
        int ec = cntE; if (ec > 128) ec = 128;
        int r = kneed;
        if (r > CTX - m) r = CTX - m;
        for (int t = 0; t < r && t < ec; ++t) {
            int best = t;
            for (int u2 = t + 1; u2 < ec; ++u2)
                if (eI[u2] < eI[best]) best = u2;
            if (best != t) {
                const int ti = eI[t]; eI[t] = eI[best]; eI[best] = ti;
                const float tv = eV[t]; eV[t] = eV[best]; eV[best] = tv;
            }
            gI[m + t] = eI[t];
            gV[m + t] = eV[t];
        }
        int have = m + (r < ec ? r : ec);
        for (int t = have; t < CTX; ++t) { gI[t] = gI[0]; gV[t] = gV[0]; }
        // deterministic order: insertion sort by index ascending
        for (int a = 1; a < CTX; ++a) {
            const int ia = gI[a];
            const float va = gV[a];
            int b2 = a - 1;
            while (b2 >= 0 && gI[b2] > ia) {
                gI[b2 + 1] = gI[b2]; gV[b2 + 1] = gV[b2]; --b2;
            }
            gI[b2 + 1] = ia;
            gV[b2 + 1] = va;
        }
    }
    __syncthreads();
    if (tid < CTX) {
        idxA[(size_t)q * CTX + tid] = gI[tid];
        sscA[(size_t)q * CTX + tid] = gV[tid];
    }
}

// diff[(q-q0)*96+c][d] = k_q[q][d] - ck[idx[q][c]][d]
__global__ void gather_diff(const float* __restrict__ k_q, const float* __restrict__ ck,
                            const int* __restrict__ idxA, int q0, float* __restrict__ diff)
{
    const int r = blockIdx.x;
    const int q = q0 + r / CTX;
    const int c = r % CTX;
    const int j = idxA[(size_t)q * CTX + c];
    const int d = threadIdx.x;
    diff[(size_t)r * D_MAIN + d] =
        k_q[(size_t)q * D_MAIN + d] - ck[(size_t)j * D_MAIN + d];
}

// softmax over 96 selected scores; x_q[q] += sum_c p_c*vv[c] + ybar*w_lab + b_lab
__global__ void combine_kernel(const float* __restrict__ sscA, const int* __restrict__ idxA,
                               const float* __restrict__ ytr, const float* __restrict__ w_lab,
                               const float* __restrict__ b_lab, const float* __restrict__ vv,
                               float* __restrict__ x_q, int q0)
{
    const int q = q0 + blockIdx.x;
    __shared__ float pr[CTX];
    __shared__ float sh_ybar;
    const int tid = threadIdx.x;
    if (tid == 0) {
        float mx = -1e30f;
        for (int c = 0; c < CTX; ++c) mx = fmaxf(mx, sscA[(size_t)q * CTX + c]);
        float sum = 0.f;
        for (int c = 0; c < CTX; ++c) {
            const float e = __expf(sscA[(size_t)q * CTX + c] - mx) ;
            pr[c] = e; sum += e;
        }
        const float inv = 1.f / sum;
        float yb = 0.f;
        for (int c = 0; c < CTX; ++c) {
            pr[c] *= inv;
            yb += pr[c] * ytr[idxA[(size_t)q * CTX + c]];
        }
        sh_ybar = yb;
    }
    __syncthreads();
    const int d = tid;
    float acc = 0.f;
    const float* vq = vv + (size_t)blockIdx.x * CTX * D_MAIN;
    for (int c = 0; c < CTX; ++c) acc += pr[c] * vq[(size_t)c * D_MAIN + d];
    x_q[(size_t)q * D_MAIN + d] += acc + sh_ybar * w_lab[d] + b_lab[d];
}

// ---------------------------------------------------------------------------
static inline void launch_gemm(hipStream_t s, const float* A, const float* B,
                               const float* bias, float biasScale, const float* resid,
                               float* C, int M, int N, int K, float alpha, int relu)
{
    dim3 g((N + TILE - 1) / TILE, (M + TILE - 1) / TILE);
    gemm_bias_act<<<g, 256, 0, s>>>(A, B, bias, biasScale, resid, C, M, N, K, alpha, relu);
}

extern "C" void kernel_launch(void* const* d_in, const int* in_sizes, int n_in,
                              void* d_out, int out_size, void* d_ws, size_t ws_size,
                              hipStream_t stream)
{
    const float* X      = (const float*)d_in[0];
    const float* Xtr    = (const float*)d_in[1];
    const float* ytr    = (const float*)d_in[2];
    const float* W_in   = (const float*)d_in[3];
    const float* b_in   = (const float*)d_in[4];
    const float* W0a    = (const float*)d_in[5];
    const float* b0a    = (const float*)d_in[6];
    const float* W0b    = (const float*)d_in[7];
    const float* b0b    = (const float*)d_in[8];
    const float* g_mix  = (const float*)d_in[9];
    const float* be_mix = (const float*)d_in[10];
    const float* W_k    = (const float*)d_in[11];
    const float* b_k    = (const float*)d_in[12];
    const float* w_lab  = (const float*)d_in[13];
    const float* b_lab  = (const float*)d_in[14];
    const float* W_t1   = (const float*)d_in[15];
    const float* b_t1   = (const float*)d_in[16];
    const float* W_t2   = (const float*)d_in[17];
    const float* g_p    = (const float*)d_in[18];
    const float* be_p   = (const float*)d_in[19];
    const float* W1a    = (const float*)d_in[20];
    const float* b1a    = (const float*)d_in[21];
    const float* W1b    = (const float*)d_in[22];
    const float* b1b    = (const float*)d_in[23];
    const float* g_h    = (const float*)d_in[24];
    const float* be_h   = (const float*)d_in[25];
    const float* W_h    = (const float*)d_in[26];
    const float* b_h    = (const float*)d_in[27];
    float* out = (float*)d_out;

    char* ws = (char*)d_ws;
    size_t off = 0;
    auto alloc = [&](size_t bytes) -> void* {
        void* p = ws + off;
        off += (bytes + 255) & ~(size_t)255;
        return p;
    };
    float* ck   = (float*)alloc((size_t)NTRAIN * D_MAIN * 4);
    float* sqc  = (float*)alloc((size_t)NTRAIN * 4);
    float* x_q  = (float*)alloc((size_t)NQ * D_MAIN * 4);
    float* h_q  = (float*)alloc((size_t)NQ * D_MAIN * 4);
    float* t_q  = (float*)alloc((size_t)NQ * D_BLOCK * 4);
    float* ln_q = (float*)alloc((size_t)NQ * D_MAIN * 4);
    float* k_q  = (float*)alloc((size_t)NQ * D_MAIN * 4);
    int*   idxA = (int*)alloc((size_t)NQ * CTX * 4);
    float* sscA = (float*)alloc((size_t)NQ * CTX * 4);

    const size_t bigOff = off;
    const size_t bigBytes = (ws_size > bigOff) ? (ws_size - bigOff) : 0;
    char* big = ws + bigOff;

    // ---------------- encode queries ----------------
    launch_gemm(stream, X,    W_in, b_in, 1.f, nullptr, h_q,  NQ, D_MAIN, D_IN, 1.f, 0);
    launch_gemm(stream, h_q,  W0a,  b0a,  1.f, nullptr, t_q,  NQ, D_BLOCK, D_MAIN, 1.f, 1);
    launch_gemm(stream, t_q,  W0b,  b0b,  1.f, h_q,     x_q,  NQ, D_MAIN, D_BLOCK, 1.f, 0);
    ln_kernel<<<(NQ + 3) / 4, 256, 0, stream>>>(x_q, g_mix, be_mix, ln_q, NQ);
    launch_gemm(stream, ln_q, W_k,  b_k,  1.f, nullptr, k_q,  NQ, D_MAIN, D_MAIN, 1.f, 0);

    // ---------------- encode train (chunked) ----------------
    {
        long Rmax = (long)(bigBytes / 5120);  // h(1024)+t(2048)+x(1024)+ln(1024) bytes/row
        int R = (int)(Rmax < 25000 ? Rmax : 25000);
        if (R < 256) R = 256;
        float* h_t  = (float*)big;
        float* t_t  = (float*)(big + (size_t)R * 256 * 4);
        float* x_t  = (float*)(big + (size_t)R * 256 * 4 + (size_t)R * 512 * 4);
        float* ln_t = (float*)(big + (size_t)R * 256 * 4 + (size_t)R * 512 * 4 + (size_t)R * 256 * 4);
        for (int r0 = 0; r0 < NTRAIN; r0 += R) {
            const int Rc = (NTRAIN - r0 < R) ? (NTRAIN - r0) : R;
            launch_gemm(stream, Xtr + (size_t)r0 * D_IN, W_in, b_in, 1.f, nullptr, h_t, Rc, D_MAIN, D_IN, 1.f, 0);
            launch_gemm(stream, h_t, W0a, b0a, 1.f, nullptr, t_t, Rc, D_BLOCK, D_MAIN, 1.f, 1);
            launch_gemm(stream, t_t, W0b, b0b, 1.f, h_t, x_t, Rc, D_MAIN, D_BLOCK, 1.f, 0);
            ln_kernel<<<(Rc + 3) / 4, 256, 0, stream>>>(x_t, g_mix, be_mix, ln_t, Rc);
            launch_gemm(stream, ln_t, W_k, b_k, 1.f, nullptr, ck + (size_t)r0 * D_MAIN, Rc, D_MAIN, D_MAIN, 1.f, 0);
        }
    }
    rowsq_kernel<<<(NTRAIN + 3) / 4, 256, 0, stream>>>(ck, sqc, NTRAIN);

    // ---------------- retrieval + context (chunked over queries) ----------------
    {
        long Qmax = (long)(bigBytes / ((size_t)NTRAIN * 4));  // scores dominate
        int Q = (int)(Qmax < 256 ? Qmax : 256);
        if (Q < 1) Q = 1;
        float* scores = (float*)big;
        float* diff = (float*)big;
        float* tt = (float*)(big + (size_t)Q * CTX * D_MAIN * 4);
        float* vv = (float*)(big + (size_t)Q * CTX * D_MAIN * 4 + (size_t)Q * CTX * D_BLOCK * 4);
        for (int q0 = 0; q0 < NQ; q0 += Q) {
            const int Qc = (NQ - q0 < Q) ? (NQ - q0) : Q;
            // scores = 2*k_q@ck^T - sqc  (row-constant -|k|^2 omitted; irrelevant)
            launch_gemm(stream, k_q + (size_t)q0 * D_MAIN, ck, sqc, -1.f, nullptr,
                        scores, Qc, NTRAIN, D_MAIN, 2.f, 0);
            topk_kernel<<<Qc, 256, 0, stream>>>(scores, NTRAIN, q0, idxA, sscA);
            gather_diff<<<Qc * CTX, 256, 0, stream>>>(k_q, ck, idxA, q0, diff);
            launch_gemm(stream, diff, W_t1, b_t1, 1.f, nullptr, tt, Qc * CTX, D_BLOCK, D_MAIN, 1.f, 1);
            launch_gemm(stream, tt, W_t2, nullptr, 0.f, nullptr, vv, Qc * CTX, D_MAIN, D_BLOCK, 1.f, 0);
            combine_kernel<<<Qc, 256, 0, stream>>>(sscA, idxA, ytr, w_lab, b_lab, vv, x_q, q0);
        }
    }

    // ---------------- predictor + head ----------------
    ln_kernel<<<(NQ + 3) / 4, 256, 0, stream>>>(x_q, g_p, be_p, ln_q, NQ);
    launch_gemm(stream, ln_q, W1a, b1a, 1.f, nullptr, t_q, NQ, D_BLOCK, D_MAIN, 1.f, 1);
    launch_gemm(stream, t_q, W1b, b1b, 1.f, x_q, x_q, NQ, D_MAIN, D_BLOCK, 1.f, 0);
    head_kernel<<<(NQ + 3) / 4, 256, 0, stream>>>(x_q, g_h, be_h, W_h, b_h, out, NQ);
}

// Round 3
// 2371.597 us; speedup vs baseline: 2.3883x; 2.3883x over previous
//
#include <hip/hip_runtime.h>
#include <hip/hip_bf16.h>
#include <cstdint>
#include <cstddef>

#define D_IN    32
#define D_MAIN  256
#define D_BLOCK 512
#define CTX     96
#define K_PRE   128
#define NQ      1024
#define NTRAIN  100000

typedef __attribute__((ext_vector_type(8))) short bf16x8;
typedef __attribute__((ext_vector_type(4))) float f32x4;
typedef __hip_bfloat16 bf;

#define GLL(gp, lp) __builtin_amdgcn_global_load_lds( \
    (const __attribute__((address_space(1))) void*)(gp), \
    (__attribute__((address_space(3))) void*)(lp), 16, 0, 0)

// ---------------------------------------------------------------------------
// Plain bf16 MFMA GEMM: C = act(alpha*(A@B^T) + biasScale*bias[n] (+resid))
// 128x128 tile, BK=32, 4 waves, 16x16x32 MFMA, XOR-swizzled LDS staging.
// ---------------------------------------------------------------------------
__global__ __launch_bounds__(256) void gemm_bf16(
    const bf* __restrict__ A, const bf* __restrict__ B,
    int M, int N, int K, float alpha,
    const float* __restrict__ bias, float biasScale,
    float* __restrict__ Cf, bf* __restrict__ Ch, int relu)
{
    __shared__ __align__(16) char smem[16384];
    const int tid = threadIdx.x;
    const int w   = tid >> 6;
    const int lam = tid & 63;
    const int bm  = blockIdx.y * 128;
    const int bn  = blockIdx.x * 128;
    const int wm  = w >> 1, wn = w & 1;

    f32x4 acc[4][4];
#pragma unroll
    for (int i = 0; i < 4; ++i)
#pragma unroll
        for (int j = 0; j < 4; ++j) acc[i][j] = (f32x4){0.f, 0.f, 0.f, 0.f};

    const int r0s  = w * 16 + (lam >> 2);
    const int slot = lam & 3;
    const int g0   = slot ^ ((r0s >> 1) & 3);
    const int g1   = slot ^ (((r0s + 64) >> 1) & 3);
    const size_t strideAB = (size_t)K * 2;
    long ga0 = bm + r0s;      if (ga0 >= M) ga0 = M - 1;
    long ga1 = bm + r0s + 64; if (ga1 >= M) ga1 = M - 1;
    long gb0 = bn + r0s;      if (gb0 >= N) gb0 = N - 1;
    long gb1 = bn + r0s + 64; if (gb1 >= N) gb1 = N - 1;
    const char* pa0 = (const char*)A + (size_t)ga0 * strideAB + 16 * g0;
    const char* pa1 = (const char*)A + (size_t)ga1 * strideAB + 16 * g1;
    const char* pb0 = (const char*)B + (size_t)gb0 * strideAB + 16 * g0;
    const char* pb1 = (const char*)B + (size_t)gb1 * strideAB + 16 * g1;

    const int sread = (lam >> 4) ^ ((lam >> 1) & 3);
    const int abase = wm * 4096 + (lam & 15) * 64 + sread * 16;
    const int bbase = 8192 + wn * 4096 + (lam & 15) * 64 + sread * 16;

    for (int k0 = 0; k0 < K; k0 += 32) {
        __syncthreads();
        const size_t kb = 2 * (size_t)k0;
        GLL(pa0 + kb, smem + w * 1024);
        GLL(pa1 + kb, smem + 4096 + w * 1024);
        GLL(pb0 + kb, smem + 8192 + w * 1024);
        GLL(pb1 + kb, smem + 12288 + w * 1024);
        asm volatile("s_waitcnt vmcnt(0)" ::: "memory");
        __syncthreads();

        bf16x8 aF[4], bF[4];
#pragma unroll
        for (int i = 0; i < 4; ++i) aF[i] = *(const bf16x8*)(smem + abase + 1024 * i);
#pragma unroll
        for (int j = 0; j < 4; ++j) bF[j] = *(const bf16x8*)(smem + bbase + 1024 * j);
#pragma unroll
        for (int i = 0; i < 4; ++i)
#pragma unroll
            for (int j = 0; j < 4; ++j)
                acc[i][j] = __builtin_amdgcn_mfma_f32_16x16x32_bf16(aF[i], bF[j], acc[i][j], 0, 0, 0);
    }

    const int col0 = bn + wn * 64 + (lam & 15);
    const int row0 = bm + wm * 64 + ((lam >> 4) << 2);
#pragma unroll
    for (int j = 0; j < 4; ++j) {
        const int col = col0 + 16 * j;
        if (col >= N) continue;
        const float bv = bias ? biasScale * bias[col] : 0.f;
#pragma unroll
        for (int i = 0; i < 4; ++i) {
#pragma unroll
            for (int r = 0; r < 4; ++r) {
                const int row = row0 + 16 * i + r;
                if (row >= M) continue;
                float v = alpha * acc[i][j][r] + bv;
                if (relu) v = fmaxf(v, 0.f);
                const size_t idx = (size_t)row * N + col;
                if (Cf) Cf[idx] = v;
                if (Ch) Ch[idx] = __float2bfloat16(v);
            }
        }
    }
}

// ---------------------------------------------------------------------------
// Split-bf16 GEMM: C = act((AH+AL)@(BH+BL)^T + bias + res) dropping AL*BL.
// Same geometry, 4 LDS tiles (32KB), 48 MFMA per K-step. ~1e-5 rel accuracy.
// ---------------------------------------------------------------------------
__global__ __launch_bounds__(256) void gemm_bf16_split(
    const bf* __restrict__ AH, const bf* __restrict__ AL,
    const bf* __restrict__ BH, const bf* __restrict__ BL,
    int M, int N, int K, const float* __restrict__ bias,
    const bf* __restrict__ resHi, const bf* __restrict__ resLo,
    float* __restrict__ Cf, bf* __restrict__ Chi, bf* __restrict__ Clo,
    bf* __restrict__ Cb, int relu)
{
    __shared__ __align__(16) char smem[32768];  // AH 0, AL 8192, BH 16384, BL 24576
    const int tid = threadIdx.x;
    const int w   = tid >> 6;
    const int lam = tid & 63;
    const int bm  = blockIdx.y * 128;
    const int bn  = blockIdx.x * 128;
    const int wm  = w >> 1, wn = w & 1;

    f32x4 acc[4][4];
#pragma unroll
    for (int i = 0; i < 4; ++i)
#pragma unroll
        for (int j = 0; j < 4; ++j) acc[i][j] = (f32x4){0.f, 0.f, 0.f, 0.f};

    const int r0s  = w * 16 + (lam >> 2);
    const int slot = lam & 3;
    const int g0   = slot ^ ((r0s >> 1) & 3);
    const int g1   = slot ^ (((r0s + 64) >> 1) & 3);
    const size_t strideAB = (size_t)K * 2;
    long ga0 = bm + r0s;      if (ga0 >= M) ga0 = M - 1;
    long ga1 = bm + r0s + 64; if (ga1 >= M) ga1 = M - 1;
    long gb0 = bn + r0s;      if (gb0 >= N) gb0 = N - 1;
    long gb1 = bn + r0s + 64; if (gb1 >= N) gb1 = N - 1;
    const size_t oa0 = (size_t)ga0 * strideAB + 16 * g0;
    const size_t oa1 = (size_t)ga1 * strideAB + 16 * g1;
    const size_t ob0 = (size_t)gb0 * strideAB + 16 * g0;
    const size_t ob1 = (size_t)gb1 * strideAB + 16 * g1;

    const int sread = (lam >> 4) ^ ((lam >> 1) & 3);
    const int abase = (lam & 15) * 64 + sread * 16;   // + wm*4096 (+8192 for L)
    const int bbase = (lam & 15) * 64 + sread * 16;   // + 16384 + wn*4096 (+8192 for L)

    for (int k0 = 0; k0 < K; k0 += 32) {
        __syncthreads();
        const size_t kb = 2 * (size_t)k0;
        GLL((const char*)AH + oa0 + kb, smem + w * 1024);
        GLL((const char*)AH + oa1 + kb, smem + 4096 + w * 1024);
        GLL((const char*)AL + oa0 + kb, smem + 8192 + w * 1024);
        GLL((const char*)AL + oa1 + kb, smem + 12288 + w * 1024);
        GLL((const char*)BH + ob0 + kb, smem + 16384 + w * 1024);
        GLL((const char*)BH + ob1 + kb, smem + 20480 + w * 1024);
        GLL((const char*)BL + ob0 + kb, smem + 24576 + w * 1024);
        GLL((const char*)BL + ob1 + kb, smem + 28672 + w * 1024);
        asm volatile("s_waitcnt vmcnt(0)" ::: "memory");
        __syncthreads();

        bf16x8 aH[4], aL[4], bH[4], bL[4];
#pragma unroll
        for (int i = 0; i < 4; ++i) {
            aH[i] = *(const bf16x8*)(smem + wm * 4096 + abase + 1024 * i);
            aL[i] = *(const bf16x8*)(smem + 8192 + wm * 4096 + abase + 1024 * i);
        }
#pragma unroll
        for (int j = 0; j < 4; ++j) {
            bH[j] = *(const bf16x8*)(smem + 16384 + wn * 4096 + bbase + 1024 * j);
            bL[j] = *(const bf16x8*)(smem + 24576 + wn * 4096 + bbase + 1024 * j);
        }
#pragma unroll
        for (int i = 0; i < 4; ++i)
#pragma unroll
            for (int j = 0; j < 4; ++j) {
                acc[i][j] = __builtin_amdgcn_mfma_f32_16x16x32_bf16(aH[i], bH[j], acc[i][j], 0, 0, 0);
                acc[i][j] = __builtin_amdgcn_mfma_f32_16x16x32_bf16(aH[i], bL[j], acc[i][j], 0, 0, 0);
                acc[i][j] = __builtin_amdgcn_mfma_f32_16x16x32_bf16(aL[i], bH[j], acc[i][j], 0, 0, 0);
            }
    }

    const int col0 = bn + wn * 64 + (lam & 15);
    const int row0 = bm + wm * 64 + ((lam >> 4) << 2);
#pragma unroll
    for (int j = 0; j < 4; ++j) {
        const int col = col0 + 16 * j;
        if (col >= N) continue;
        const float bv = bias ? bias[col] : 0.f;
#pragma unroll
        for (int i = 0; i < 4; ++i) {
#pragma unroll
            for (int r = 0; r < 4; ++r) {
                const int row = row0 + 16 * i + r;
                if (row >= M) continue;
                float v = acc[i][j][r] + bv;
                const size_t idx = (size_t)row * N + col;
                if (resHi) v += __bfloat162float(resHi[idx]) + __bfloat162float(resLo[idx]);
                if (relu) v = fmaxf(v, 0.f);
                if (Cf) Cf[idx] = v;
                if (Cb) Cb[idx] = __float2bfloat16(v);
                if (Chi) {
                    const float h = __bfloat162float(__float2bfloat16(v));
                    Chi[idx] = __float2bfloat16(v);
                    Clo[idx] = __float2bfloat16(v - h);
                }
            }
        }
    }
}

// ---------------------------------------------------------------------------
// fp32 GEMM (query encoder / predictor; exact path)
// ---------------------------------------------------------------------------
#define TILE 64
#define KT   16
__global__ __launch_bounds__(256) void gemm_bias_act(
    const float* __restrict__ A, const float* __restrict__ B,
    const float* __restrict__ bias, float biasScale,
    const float* __restrict__ resid,
    float* __restrict__ C,
    int M, int N, int K, float alpha, int relu)
{
    __shared__ float As[KT][TILE + 4];
    __shared__ float Bs[KT][TILE + 4];
    const int bm = blockIdx.y * TILE;
    const int bn = blockIdx.x * TILE;
    const int tid = threadIdx.x;
    const int tx = tid & 15;
    const int ty = tid >> 4;
    const int lm = tid >> 2;
    const int lk = (tid & 3) * 4;

    float acc[4][4];
#pragma unroll
    for (int i = 0; i < 4; ++i)
#pragma unroll
        for (int j = 0; j < 4; ++j) acc[i][j] = 0.f;

    for (int k0 = 0; k0 < K; k0 += KT) {
        {
            const int gm = bm + lm;
            float4 v = make_float4(0.f, 0.f, 0.f, 0.f);
            if (gm < M) v = *reinterpret_cast<const float4*>(A + (size_t)gm * K + k0 + lk);
            As[lk + 0][lm] = v.x; As[lk + 1][lm] = v.y;
            As[lk + 2][lm] = v.z; As[lk + 3][lm] = v.w;
            const int gn = bn + lm;
            float4 u = make_float4(0.f, 0.f, 0.f, 0.f);
            if (gn < N) u = *reinterpret_cast<const float4*>(B + (size_t)gn * K + k0 + lk);
            Bs[lk + 0][lm] = u.x; Bs[lk + 1][lm] = u.y;
            Bs[lk + 2][lm] = u.z; Bs[lk + 3][lm] = u.w;
        }
        __syncthreads();
#pragma unroll
        for (int kk = 0; kk < KT; ++kk) {
            float aa[4], bb[4];
#pragma unroll
            for (int i = 0; i < 4; ++i) aa[i] = As[kk][ty * 4 + i];
#pragma unroll
            for (int j = 0; j < 4; ++j) bb[j] = Bs[kk][tx * 4 + j];
#pragma unroll
            for (int i = 0; i < 4; ++i)
#pragma unroll
                for (int j = 0; j < 4; ++j) acc[i][j] += aa[i] * bb[j];
        }
        __syncthreads();
    }
#pragma unroll
    for (int i = 0; i < 4; ++i) {
        const int gm = bm + ty * 4 + i;
        if (gm >= M) continue;
#pragma unroll
        for (int j = 0; j < 4; ++j) {
            const int gn = bn + tx * 4 + j;
            if (gn >= N) continue;
            float v = alpha * acc[i][j];
            if (bias)  v += biasScale * bias[gn];
            if (resid) v += resid[(size_t)gm * N + gn];
            if (relu)  v = fmaxf(v, 0.f);
            C[(size_t)gm * N + gn] = v;
        }
    }
}

// ---------------------------------------------------------------------------
// LayerNorm variants + small helpers
// ---------------------------------------------------------------------------
__global__ void ln_kernel(const float* __restrict__ X, const float* __restrict__ g,
                          const float* __restrict__ b, float* __restrict__ Y, int M)
{
    const int row = blockIdx.x * 4 + (threadIdx.x >> 6);
    const int lane = threadIdx.x & 63;
    if (row >= M) return;
    const float* x = X + (size_t)row * D_MAIN;
    float v[4]; float s = 0.f;
#pragma unroll
    for (int i = 0; i < 4; ++i) { v[i] = x[lane + 64 * i]; s += v[i]; }
#pragma unroll
    for (int o = 32; o > 0; o >>= 1) s += __shfl_xor(s, o);
    const float mu = s * (1.f / D_MAIN);
    float vs = 0.f;
#pragma unroll
    for (int i = 0; i < 4; ++i) { const float d = v[i] - mu; vs += d * d; }
#pragma unroll
    for (int o = 32; o > 0; o >>= 1) vs += __shfl_xor(vs, o);
    const float inv = rsqrtf(vs * (1.f / D_MAIN) + 1e-5f);
    float* y = Y + (size_t)row * D_MAIN;
#pragma unroll
    for (int i = 0; i < 4; ++i) {
        const int d = lane + 64 * i;
        y[d] = (v[i] - mu) * inv * g[d] + b[d];
    }
}

__global__ void ln_split_kernel(const float* __restrict__ X, const float* __restrict__ g,
                                const float* __restrict__ b,
                                bf* __restrict__ Yhi, bf* __restrict__ Ylo, int M)
{
    const int row = blockIdx.x * 4 + (threadIdx.x >> 6);
    const int lane = threadIdx.x & 63;
    if (row >= M) return;
    const float* x = X + (size_t)row * D_MAIN;
    float v[4]; float s = 0.f;
#pragma unroll
    for (int i = 0; i < 4; ++i) { v[i] = x[lane + 64 * i]; s += v[i]; }
#pragma unroll
    for (int o = 32; o > 0; o >>= 1) s += __shfl_xor(s, o);
    const float mu = s * (1.f / D_MAIN);
    float vs = 0.f;
#pragma unroll
    for (int i = 0; i < 4; ++i) { const float d = v[i] - mu; vs += d * d; }
#pragma unroll
    for (int o = 32; o > 0; o >>= 1) vs += __shfl_xor(vs, o);
    const float inv = rsqrtf(vs * (1.f / D_MAIN) + 1e-5f);
#pragma unroll
    for (int i = 0; i < 4; ++i) {
        const int d = lane + 64 * i;
        const float val = (v[i] - mu) * inv * g[d] + b[d];
        const bf h = __float2bfloat16(val);
        Yhi[(size_t)row * D_MAIN + d] = h;
        Ylo[(size_t)row * D_MAIN + d] = __float2bfloat16(val - __bfloat162float(h));
    }
}

__global__ void rowsq_kernel(const float* __restrict__ X, float* __restrict__ sq, int M)
{
    const int row = blockIdx.x * 4 + (threadIdx.x >> 6);
    const int lane = threadIdx.x & 63;
    if (row >= M) return;
    const float* x = X + (size_t)row * D_MAIN;
    float s = 0.f;
#pragma unroll
    for (int i = 0; i < 4; ++i) { const float v = x[lane + 64 * i]; s += v * v; }
#pragma unroll
    for (int o = 32; o > 0; o >>= 1) s += __shfl_xor(s, o);
    if (lane == 0) sq[row] = s;
}

__global__ void head_kernel(const float* __restrict__ X, const float* __restrict__ g,
                            const float* __restrict__ b, const float* __restrict__ W,
                            const float* __restrict__ bh, float* __restrict__ out, int M)
{
    const int row = blockIdx.x * 4 + (threadIdx.x >> 6);
    const int lane = threadIdx.x & 63;
    if (row >= M) return;
    const float* x = X + (size_t)row * D_MAIN;
    float v[4]; float s = 0.f;
#pragma unroll
    for (int i = 0; i < 4; ++i) { v[i] = x[lane + 64 * i]; s += v[i]; }
#pragma unroll
    for (int o = 32; o > 0; o >>= 1) s += __shfl_xor(s, o);
    const float mu = s * (1.f / D_MAIN);
    float vs = 0.f;
#pragma unroll
    for (int i = 0; i < 4; ++i) { const float d = v[i] - mu; vs += d * d; }
#pragma unroll
    for (int o = 32; o > 0; o >>= 1) vs += __shfl_xor(vs, o);
    const float inv = rsqrtf(vs * (1.f / D_MAIN) + 1e-5f);
    float acc = 0.f;
#pragma unroll
    for (int i = 0; i < 4; ++i) {
        const int d = lane + 64 * i;
        float o_ = (v[i] - mu) * inv * g[d] + b[d];
        o_ = fmaxf(o_, 0.f);
        acc += o_ * W[d];
    }
#pragma unroll
    for (int o = 32; o > 0; o >>= 1) acc += __shfl_xor(acc, o);
    if (lane == 0) out[row] = acc + bh[0];
}

__global__ void f2b_kernel(const float* __restrict__ in, bf* __restrict__ out, int n)
{
    const int i = blockIdx.x * 256 + threadIdx.x;
    if (i < n) out[i] = __float2bfloat16(in[i]);
}

__global__ void f2b_split_kernel(const float* __restrict__ in,
                                 bf* __restrict__ hi, bf* __restrict__ lo, int n)
{
    const int i = blockIdx.x * 256 + threadIdx.x;
    if (i < n) {
        const float v = in[i];
        const bf h = __float2bfloat16(v);
        hi[i] = h;
        lo[i] = __float2bfloat16(v - __bfloat162float(h));
    }
}

// ---------------------------------------------------------------------------
// Preselect top-128 per row (radix on float-ordered keys); set is exact for
// the bf16 scores; order within output irrelevant (re-ranked exactly after).
// ---------------------------------------------------------------------------
#define TK_CAP 3584

__global__ __launch_bounds__(256) void topk_kernel(
    const float* __restrict__ scores, int N, int q0, int* __restrict__ idxOut)
{
    const int q = q0 + blockIdx.x;
    const float* row = scores + (size_t)blockIdx.x * N;
    const int tid = threadIdx.x;

    __shared__ union {
        unsigned hist[2][4096];
        struct { int ia[TK_CAP]; unsigned ka[TK_CAP]; int ib[TK_CAP]; unsigned kb[TK_CAP]; } c;
    } u;
    __shared__ unsigned hist2[256];
    __shared__ unsigned cs[256];
    __shared__ int gI[K_PRE];
    __shared__ int cntG, cntE, sh_bnd, sh_need;

    for (int bin = tid; bin < 2 * 4096; bin += 256) ((unsigned*)u.hist)[bin] = 0;
    __syncthreads();
    const int rep = (tid >> 6) & 1;
    const float4* row4 = (const float4*)row;
    const int N4 = N >> 2;
    for (int i = tid; i < N4; i += 256) {
        const float4 v = row4[i];
        const float f[4] = {v.x, v.y, v.z, v.w};
#pragma unroll
        for (int c = 0; c < 4; ++c) {
            const unsigned uu = __float_as_uint(f[c]);
            const unsigned key = (uu & 0x80000000u) ? ~uu : (uu | 0x80000000u);
            atomicAdd(&u.hist[rep][key >> 20], 1u);
        }
    }
    __syncthreads();
    unsigned csum = 0;
    for (int bin = tid * 16; bin < tid * 16 + 16; ++bin) {
        const unsigned v = u.hist[0][bin] + u.hist[1][bin];
        u.hist[0][bin] = v; csum += v;
    }
    cs[tid] = csum;
    __syncthreads();
    if (tid == 0) {
        unsigned cum = 0; int ch = 0;
        for (int t = 255; t >= 0; --t) {
            if (cum + cs[t] >= (unsigned)K_PRE) { ch = t; break; }
            cum += cs[t];
        }
        int bnd = ch * 16;
        for (int bin = ch * 16 + 15; bin >= ch * 16; --bin) {
            const unsigned c = u.hist[0][bin];
            if (cum + c >= (unsigned)K_PRE) { bnd = bin; break; }
            cum += c;
        }
        sh_bnd = bnd; sh_need = K_PRE - (int)cum;
        cntG = 0; cntE = 0;
    }
    __syncthreads();
    const unsigned bnd12 = (unsigned)sh_bnd;

    for (int i = tid; i < N4; i += 256) {
        const float4 v = row4[i];
        const float f[4] = {v.x, v.y, v.z, v.w};
#pragma unroll
        for (int c = 0; c < 4; ++c) {
            const unsigned uu = __float_as_uint(f[c]);
            const unsigned key = (uu & 0x80000000u) ? ~uu : (uu | 0x80000000u);
            const unsigned b12 = key >> 20;
            if (b12 > bnd12) {
                const int p = atomicAdd(&cntG, 1);
                if (p < K_PRE) gI[p] = 4 * i + c;
            } else if (b12 == bnd12) {
                const int p = atomicAdd(&cntE, 1);
                if (p < TK_CAP) { u.c.ia[p] = 4 * i + c; u.c.ka[p] = key; }
            }
        }
    }
    __syncthreads();

    int E = cntE < TK_CAP ? cntE : TK_CAP;
    int need = sh_need;
    int curA = 1;
    for (int lvl = 0; lvl < 3 && need > 0; ++lvl) {
        const int sh = (lvl == 0) ? 12 : (lvl == 1) ? 4 : 0;
        const unsigned msk = (lvl == 2) ? 15u : 255u;
        const int nb = (lvl == 2) ? 16 : 256;
        for (int bin = tid; bin < nb; bin += 256) hist2[bin] = 0;
        if (tid == 0) cntE = 0;
        __syncthreads();
        const int* ci = curA ? u.c.ia : u.c.ib;
        const unsigned* ki = curA ? u.c.ka : u.c.kb;
        int* io = curA ? u.c.ib : u.c.ia;
        unsigned* ko = curA ? u.c.kb : u.c.ka;
        for (int e = tid; e < E; e += 256) atomicAdd(&hist2[(ki[e] >> sh) & msk], 1u);
        __syncthreads();
        if (tid == 0) {
            unsigned cum = 0; int b2 = 0;
            for (int bin = nb - 1; bin >= 0; --bin) {
                const unsigned c = hist2[bin];
                if (cum + c >= (unsigned)need) { b2 = bin; break; }
                cum += c;
            }
            sh_bnd = b2; sh_need = need - (int)cum;
        }
        __syncthreads();
        const unsigned b2 = (unsigned)sh_bnd;
        for (int e = tid; e < E; e += 256) {
            const unsigned f = (ki[e] >> sh) & msk;
            if (f > b2) {
                const int p = atomicAdd(&cntG, 1);
                if (p < K_PRE) gI[p] = ci[e];
            } else if (f == b2) {
                const int p = atomicAdd(&cntE, 1);
                if (p < TK_CAP) { io[p] = ci[e]; ko[p] = ki[e]; }
            }
        }
        __syncthreads();
        E = cntE < TK_CAP ? cntE : TK_CAP;
        need = sh_need;
        curA ^= 1;
        __syncthreads();
    }

    if (tid == 0) {
        if (need > 0) {
            const int* ci = curA ? u.c.ia : u.c.ib;
            int last = -1;
            for (int t = 0; t < need; ++t) {
                int best = 0x7fffffff;
                for (int e = 0; e < E; ++e) {
                    const int v = ci[e];
                    if (v > last && v < best) best = v;
                }
                const int p = cntG + t;
                if (p < K_PRE && best != 0x7fffffff) { gI[p] = best; last = best; }
            }
            cntG += need;
        }
        int tot = cntG < K_PRE ? cntG : K_PRE;
        if (tot == 0) { gI[0] = 0; tot = 1; }
        for (int t = tot; t < K_PRE; ++t) gI[t] = gI[0];
    }
    __syncthreads();
    if (tid < K_PRE) idxOut[(size_t)q * K_PRE + tid] = gI[tid];
}

// ---------------------------------------------------------------------------
// Exact re-rank: fp32 d2 over 128 candidates, top-96 with (d2, idx) tie rule,
// output idx sorted ascending + exact sims = -d2. One block per query.
// ---------------------------------------------------------------------------
__global__ __launch_bounds__(256) void rerank_kernel(
    const float* __restrict__ k_q, const float* __restrict__ ck,
    const int* __restrict__ idx128, int* __restrict__ idx96,
    float* __restrict__ sims96)
{
    const int q = blockIdx.x;
    const int tid = threadIdx.x;
    const int w = tid >> 6, lam = tid & 63;
    __shared__ float kq[D_MAIN];
    __shared__ unsigned long long keys[K_PRE];
    kq[tid] = k_q[(size_t)q * D_MAIN + tid];
    __syncthreads();

    for (int c = w * 32; c < w * 32 + 32; ++c) {
        const int j = idx128[(size_t)q * K_PRE + c];
        const float4 cv = *(const float4*)(ck + (size_t)j * D_MAIN + lam * 4);
        const float d0 = kq[lam * 4 + 0] - cv.x;
        const float d1 = kq[lam * 4 + 1] - cv.y;
        const float d2_ = kq[lam * 4 + 2] - cv.z;
        const float d3 = kq[lam * 4 + 3] - cv.w;
        float s = d0 * d0 + d1 * d1 + d2_ * d2_ + d3 * d3;
#pragma unroll
        for (int o = 32; o > 0; o >>= 1) s += __shfl_xor(s, o);
        if (lam == 0)
            keys[c] = ((unsigned long long)__float_as_uint(s) << 32) | (unsigned)j;
    }
    __syncthreads();

    // bitonic sort ascending: (d2 asc, idx asc)
    for (int k = 2; k <= K_PRE; k <<= 1) {
        for (int j = k >> 1; j > 0; j >>= 1) {
            if (tid < K_PRE) {
                const int ixj = tid ^ j;
                if (ixj > tid) {
                    const bool up = ((tid & k) == 0);
                    const unsigned long long a = keys[tid], b2 = keys[ixj];
                    if ((a > b2) == up) { keys[tid] = b2; keys[ixj] = a; }
                }
            }
            __syncthreads();
        }
    }
    // keep first 96; re-key as (idx<<32)|d2bits and sort by idx ascending
    unsigned long long k2 = ~0ull;
    if (tid < CTX) k2 = (keys[tid] << 32) | (keys[tid] >> 32);
    __syncthreads();
    if (tid < K_PRE) keys[tid] = k2;
    __syncthreads();
    for (int k = 2; k <= K_PRE; k <<= 1) {
        for (int j = k >> 1; j > 0; j >>= 1) {
            if (tid < K_PRE) {
                const int ixj = tid ^ j;
                if (ixj > tid) {
                    const bool up = ((tid & k) == 0);
                    const unsigned long long a = keys[tid], b2 = keys[ixj];
                    if ((a > b2) == up) { keys[tid] = b2; keys[ixj] = a; }
                }
            }
            __syncthreads();
        }
    }
    if (tid < CTX) {
        idx96[(size_t)q * CTX + tid] = (int)(keys[tid] >> 32);
        sims96[(size_t)q * CTX + tid] = -__uint_as_float((unsigned)(keys[tid] & 0xffffffffu));
    }
}

// diff[(q-q0)*96+c][d] = bf16(k_q[q][d] - ck[idx[q][c]][d])
__global__ void gather_diff(const float* __restrict__ k_q, const float* __restrict__ ck,
                            const int* __restrict__ idxA, int q0, bf* __restrict__ diff)
{
    const int r = blockIdx.x;
    const int q = q0 + r / CTX;
    const int c = r % CTX;
    const int j = idxA[(size_t)q * CTX + c];
    const int d = threadIdx.x;
    const float df = k_q[(size_t)q * D_MAIN + d] - ck[(size_t)j * D_MAIN + d];
    diff[(size_t)r * D_MAIN + d] = __float2bfloat16(df);
}

__global__ void combine_kernel(const float* __restrict__ sscA, const int* __restrict__ idxA,
                               const float* __restrict__ ytr, const float* __restrict__ w_lab,
                               const float* __restrict__ b_lab, const float* __restrict__ vv,
                               float* __restrict__ x_q, int q0)
{
    const int q = q0 + blockIdx.x;
    __shared__ float pr[CTX];
    __shared__ float sh_ybar;
    const int tid = threadIdx.x;
    if (tid == 0) {
        float mx = -1e30f;
        for (int c = 0; c < CTX; ++c) mx = fmaxf(mx, sscA[(size_t)q * CTX + c]);
        float sum = 0.f;
        for (int c = 0; c < CTX; ++c) {
            const float e = __expf(sscA[(size_t)q * CTX + c] - mx);
            pr[c] = e; sum += e;
        }
        const float inv = 1.f / sum;
        float yb = 0.f;
        for (int c = 0; c < CTX; ++c) {
            pr[c] *= inv;
            yb += pr[c] * ytr[idxA[(size_t)q * CTX + c]];
        }
        sh_ybar = yb;
    }
    __syncthreads();
    const int d = tid;
    float acc = 0.f;
    const float* vq = vv + (size_t)blockIdx.x * CTX * D_MAIN;
    for (int c = 0; c < CTX; ++c) acc += pr[c] * vq[(size_t)c * D_MAIN + d];
    x_q[(size_t)q * D_MAIN + d] += acc + sh_ybar * w_lab[d] + b_lab[d];
}

// ---------------------------------------------------------------------------
extern "C" void kernel_launch(void* const* d_in, const int* in_sizes, int n_in,
                              void* d_out, int out_size, void* d_ws, size_t ws_size,
                              hipStream_t stream)
{
    const float* X      = (const float*)d_in[0];
    const float* Xtr    = (const float*)d_in[1];
    const float* ytr    = (const float*)d_in[2];
    const float* W_in   = (const float*)d_in[3];
    const float* b_in   = (const float*)d_in[4];
    const float* W0a    = (const float*)d_in[5];
    const float* b0a    = (const float*)d_in[6];
    const float* W0b    = (const float*)d_in[7];
    const float* b0b    = (const float*)d_in[8];
    const float* g_mix  = (const float*)d_in[9];
    const float* be_mix = (const float*)d_in[10];
    const float* W_k    = (const float*)d_in[11];
    const float* b_k    = (const float*)d_in[12];
    const float* w_lab  = (const float*)d_in[13];
    const float* b_lab  = (const float*)d_in[14];
    const float* W_t1   = (const float*)d_in[15];
    const float* b_t1   = (const float*)d_in[16];
    const float* W_t2   = (const float*)d_in[17];
    const float* g_p    = (const float*)d_in[18];
    const float* be_p   = (const float*)d_in[19];
    const float* W1a    = (const float*)d_in[20];
    const float* b1a    = (const float*)d_in[21];
    const float* W1b    = (const float*)d_in[22];
    const float* b1b    = (const float*)d_in[23];
    const float* g_h    = (const float*)d_in[24];
    const float* be_h   = (const float*)d_in[25];
    const float* W_h    = (const float*)d_in[26];
    const float* b_h    = (const float*)d_in[27];
    float* out = (float*)d_out;

    char* ws = (char*)d_ws;
    size_t off = 0;
    auto alloc = [&](size_t bytes) -> void* {
        void* p = ws + off;
        off += (bytes + 255) & ~(size_t)255;
        return p;
    };
    float* ck    = (float*)alloc((size_t)NTRAIN * D_MAIN * 4);
    bf*    ckh   = (bf*)   alloc((size_t)NTRAIN * D_MAIN * 2);
    float* sqc   = (float*)alloc((size_t)NTRAIN * 4);
    bf*    XtrH  = (bf*)   alloc((size_t)NTRAIN * D_IN * 2);
    bf*    XtrL  = (bf*)   alloc((size_t)NTRAIN * D_IN * 2);
    bf*    WinH  = (bf*)   alloc((size_t)D_MAIN * D_IN * 2);
    bf*    WinL  = (bf*)   alloc((size_t)D_MAIN * D_IN * 2);
    bf*    W0aH  = (bf*)   alloc((size_t)D_BLOCK * D_MAIN * 2);
    bf*    W0aL  = (bf*)   alloc((size_t)D_BLOCK * D_MAIN * 2);
    bf*    W0bH  = (bf*)   alloc((size_t)D_MAIN * D_BLOCK * 2);
    bf*    W0bL  = (bf*)   alloc((size_t)D_MAIN * D_BLOCK * 2);
    bf*    WkH   = (bf*)   alloc((size_t)D_MAIN * D_MAIN * 2);
    bf*    WkL   = (bf*)   alloc((size_t)D_MAIN * D_MAIN * 2);
    bf*    Wt1b  = (bf*)   alloc((size_t)D_BLOCK * D_MAIN * 2);
    bf*    Wt2b  = (bf*)   alloc((size_t)D_MAIN * D_BLOCK * 2);
    float* x_q   = (float*)alloc((size_t)NQ * D_MAIN * 4);
    float* h_q   = (float*)alloc((size_t)NQ * D_MAIN * 4);
    float* t_q   = (float*)alloc((size_t)NQ * D_BLOCK * 4);
    float* ln_q  = (float*)alloc((size_t)NQ * D_MAIN * 4);
    float* k_q   = (float*)alloc((size_t)NQ * D_MAIN * 4);
    bf*    k_qb  = (bf*)   alloc((size_t)NQ * D_MAIN * 2);
    int*   idx128 = (int*) alloc((size_t)NQ * K_PRE * 4);
    int*   idxA  = (int*)  alloc((size_t)NQ * CTX * 4);
    float* sscA  = (float*)alloc((size_t)NQ * CTX * 4);

    const size_t bigOff = off;
    const size_t bigBytes = (ws_size > bigOff) ? (ws_size - bigOff) : 0;
    char* big = ws + bigOff;

    auto f2b = [&](const float* in, bf* o, int n) {
        f2b_kernel<<<(n + 255) / 256, 256, 0, stream>>>(in, o, n);
    };
    auto f2bs = [&](const float* in, bf* hi, bf* lo, int n) {
        f2b_split_kernel<<<(n + 255) / 256, 256, 0, stream>>>(in, hi, lo, n);
    };

    f2bs(W_in, WinH, WinL, D_MAIN * D_IN);
    f2bs(W0a,  W0aH, W0aL, D_BLOCK * D_MAIN);
    f2bs(W0b,  W0bH, W0bL, D_MAIN * D_BLOCK);
    f2bs(W_k,  WkH,  WkL,  D_MAIN * D_MAIN);
    f2bs(Xtr,  XtrH, XtrL, NTRAIN * D_IN);
    f2b(W_t1, Wt1b, D_BLOCK * D_MAIN);
    f2b(W_t2, Wt2b, D_MAIN * D_BLOCK);

    // ---------------- encode queries (fp32 exact) ----------------
    launch_gemm_fp32: ;
    {
        dim3 g1((D_MAIN + TILE - 1) / TILE, (NQ + TILE - 1) / TILE);
        gemm_bias_act<<<g1, 256, 0, stream>>>(X, W_in, b_in, 1.f, nullptr, h_q, NQ, D_MAIN, D_IN, 1.f, 0);
        dim3 g2((D_BLOCK + TILE - 1) / TILE, (NQ + TILE - 1) / TILE);
        gemm_bias_act<<<g2, 256, 0, stream>>>(h_q, W0a, b0a, 1.f, nullptr, t_q, NQ, D_BLOCK, D_MAIN, 1.f, 1);
        gemm_bias_act<<<g1, 256, 0, stream>>>(t_q, W0b, b0b, 1.f, h_q, x_q, NQ, D_MAIN, D_BLOCK, 1.f, 0);
        ln_kernel<<<(NQ + 3) / 4, 256, 0, stream>>>(x_q, g_mix, be_mix, ln_q, NQ);
        gemm_bias_act<<<g1, 256, 0, stream>>>(ln_q, W_k, b_k, 1.f, nullptr, k_q, NQ, D_MAIN, D_MAIN, 1.f, 0);
        f2b_kernel<<<(NQ * D_MAIN + 255) / 256, 256, 0, stream>>>(k_q, k_qb, NQ * D_MAIN);
    }

    // ---------------- encode train (split-bf16 MFMA, chunked) ----------------
    {
        long Rmax = (long)(bigBytes / 5120);  // hH/hL 1K, tH/tL 2K, x 1K, lnH/lnL 1K
        int R = (int)(Rmax < 50048 ? Rmax : 50048);
        R &= ~127;
        if (R < 128) R = 128;
        bf*    hH  = (bf*)big;
        bf*    hL  = (bf*)(big + (size_t)R * 512);
        bf*    tH  = (bf*)(big + (size_t)R * 1024);
        bf*    tL  = (bf*)(big + (size_t)R * 2048);
        float* x_f = (float*)(big + (size_t)R * 3072);
        bf*    lnH = (bf*)(big + (size_t)R * 4096);
        bf*    lnL = (bf*)(big + (size_t)R * 4608);
        for (int r0 = 0; r0 < NTRAIN; r0 += R) {
            const int Rc = (NTRAIN - r0 < R) ? (NTRAIN - r0) : R;
            dim3 gA(2, (Rc + 127) / 128);   // N=256
            dim3 gB(4, (Rc + 127) / 128);   // N=512
            gemm_bf16_split<<<gA, 256, 0, stream>>>(XtrH + (size_t)r0 * D_IN, XtrL + (size_t)r0 * D_IN,
                WinH, WinL, Rc, D_MAIN, D_IN, b_in, nullptr, nullptr,
                nullptr, hH, hL, nullptr, 0);
            gemm_bf16_split<<<gB, 256, 0, stream>>>(hH, hL, W0aH, W0aL, Rc, D_BLOCK, D_MAIN,
                b0a, nullptr, nullptr, nullptr, tH, tL, nullptr, 1);
            gemm_bf16_split<<<gA, 256, 0, stream>>>(tH, tL, W0bH, W0bL, Rc, D_MAIN, D_BLOCK,
                b0b, hH, hL, x_f, nullptr, nullptr, nullptr, 0);
            ln_split_kernel<<<(Rc + 3) / 4, 256, 0, stream>>>(x_f, g_mix, be_mix, lnH, lnL, Rc);
            gemm_bf16_split<<<gA, 256, 0, stream>>>(lnH, lnL, WkH, WkL, Rc, D_MAIN, D_MAIN,
                b_k, nullptr, nullptr, ck + (size_t)r0 * D_MAIN, nullptr, nullptr,
                ckh + (size_t)r0 * D_MAIN, 0);
        }
    }
    rowsq_kernel<<<(NTRAIN + 3) / 4, 256, 0, stream>>>(ck, sqc, NTRAIN);

    // ---------------- phase A: scores (bf16) + preselect 128 ----------------
    {
        long Qmax = (long)(bigBytes / ((size_t)NTRAIN * 4));
        int Q = (int)(Qmax < NQ ? Qmax : NQ);
        if (Q < 1) Q = 1;
        float* scores = (float*)big;
        for (int q0 = 0; q0 < NQ; q0 += Q) {
            const int Qc = (NQ - q0 < Q) ? (NQ - q0) : Q;
            dim3 gs((NTRAIN + 127) / 128, (Qc + 127) / 128);
            gemm_bf16<<<gs, 256, 0, stream>>>(k_qb + (size_t)q0 * D_MAIN, ckh, Qc, NTRAIN, D_MAIN,
                2.f, sqc, -1.f, scores, nullptr, 0);
            topk_kernel<<<Qc, 256, 0, stream>>>(scores, NTRAIN, q0, idx128);
        }
    }

    // ---------------- phase B: exact re-rank to top-96 ----------------
    rerank_kernel<<<NQ, 256, 0, stream>>>(k_q, ck, idx128, idxA, sscA);

    // ---------------- phase C: values MLP + combine (chunked) ----------------
    {
        const size_t perQ = (size_t)CTX * (D_MAIN * 2 + D_BLOCK * 2 + D_MAIN * 4); // 245760
        long Qmax = (long)(bigBytes / perQ);
        int Q = (int)(Qmax < NQ ? Qmax : NQ);
        if (Q < 1) Q = 1;
        for (int q0 = 0; q0 < NQ; q0 += Q) {
            const int Qc = (NQ - q0 < Q) ? (NQ - q0) : Q;
            bf*    diff = (bf*)big;
            bf*    tt   = (bf*)(big + (size_t)Qc * CTX * D_MAIN * 2);
            float* vv   = (float*)(big + (size_t)Qc * CTX * D_MAIN * 2 + (size_t)Qc * CTX * D_BLOCK * 2);
            gather_diff<<<Qc * CTX, 256, 0, stream>>>(k_q, ck, idxA, q0, diff);
            dim3 g1((D_BLOCK + 127) / 128, (Qc * CTX + 127) / 128);
            gemm_bf16<<<g1, 256, 0, stream>>>(diff, Wt1b, Qc * CTX, D_BLOCK, D_MAIN,
                1.f, b_t1, 1.f, nullptr, tt, 1);
            dim3 g2((D_MAIN + 127) / 128, (Qc * CTX + 127) / 128);
            gemm_bf16<<<g2, 256, 0, stream>>>(tt, Wt2b, Qc * CTX, D_MAIN, D_BLOCK,
                1.f, nullptr, 0.f, vv, nullptr, 0);
            combine_kernel<<<Qc, 256, 0, stream>>>(sscA, idxA, ytr, w_lab, b_lab, vv, x_q, q0);
        }
    }

    // ---------------- predictor + head (fp32 exact) ----------------
    {
        dim3 g1((D_MAIN + TILE - 1) / TILE, (NQ + TILE - 1) / TILE);
        dim3 g2((D_BLOCK + TILE - 1) / TILE, (NQ + TILE - 1) / TILE);
        ln_kernel<<<(NQ + 3) / 4, 256, 0, stream>>>(x_q, g_p, be_p, ln_q, NQ);
        gemm_bias_act<<<g2, 256, 0, stream>>>(ln_q, W1a, b1a, 1.f, nullptr, t_q, NQ, D_BLOCK, D_MAIN, 1.f, 1);
        gemm_bias_act<<<g1, 256, 0, stream>>>(t_q, W1b, b1b, 1.f, x_q, x_q, NQ, D_MAIN, D_BLOCK, 1.f, 0);
        head_kernel<<<(NQ + 3) / 4, 256, 0, stream>>>(x_q, g_h, be_h, W_h, b_h, out, NQ);
    }
}

// Round 4
// 2358.828 us; speedup vs baseline: 2.4013x; 1.0054x over previous
//
#include <hip/hip_runtime.h>
#include <hip/hip_bf16.h>
#include <cstdint>
#include <cstddef>

#define D_IN    32
#define D_MAIN  256
#define D_BLOCK 512
#define CTX     96
#define K_PRE   128
#define NQ      1024
#define NTRAIN  100000
#define SEG     8
#define EQCAP   4096

typedef __attribute__((ext_vector_type(8))) short bf16x8;
typedef __attribute__((ext_vector_type(4))) float f32x4;
typedef __hip_bfloat16 bf;

#define GLL(gp, lp) __builtin_amdgcn_global_load_lds( \
    (const __attribute__((address_space(1))) void*)(gp), \
    (__attribute__((address_space(3))) void*)(lp), 16, 0, 0)

// ---------------------------------------------------------------------------
// Plain bf16 MFMA GEMM: C = act(alpha*(A@B^T) + biasScale*bias[n])
// 128x128 tile, BK=32, 4 waves, 16x16x32 MFMA, XOR-swizzled LDS staging.
// ---------------------------------------------------------------------------
__global__ __launch_bounds__(256) void gemm_bf16(
    const bf* __restrict__ A, const bf* __restrict__ B,
    int M, int N, int K, float alpha,
    const float* __restrict__ bias, float biasScale,
    float* __restrict__ Cf, bf* __restrict__ Ch, int relu)
{
    __shared__ __align__(16) char smem[16384];
    const int tid = threadIdx.x;
    const int w   = tid >> 6;
    const int lam = tid & 63;
    const int bm  = blockIdx.y * 128;
    const int bn  = blockIdx.x * 128;
    const int wm  = w >> 1, wn = w & 1;

    f32x4 acc[4][4];
#pragma unroll
    for (int i = 0; i < 4; ++i)
#pragma unroll
        for (int j = 0; j < 4; ++j) acc[i][j] = (f32x4){0.f, 0.f, 0.f, 0.f};

    const int r0s  = w * 16 + (lam >> 2);
    const int slot = lam & 3;
    const int g0   = slot ^ ((r0s >> 1) & 3);
    const int g1   = slot ^ (((r0s + 64) >> 1) & 3);
    const size_t strideAB = (size_t)K * 2;
    long ga0 = bm + r0s;      if (ga0 >= M) ga0 = M - 1;
    long ga1 = bm + r0s + 64; if (ga1 >= M) ga1 = M - 1;
    long gb0 = bn + r0s;      if (gb0 >= N) gb0 = N - 1;
    long gb1 = bn + r0s + 64; if (gb1 >= N) gb1 = N - 1;
    const char* pa0 = (const char*)A + (size_t)ga0 * strideAB + 16 * g0;
    const char* pa1 = (const char*)A + (size_t)ga1 * strideAB + 16 * g1;
    const char* pb0 = (const char*)B + (size_t)gb0 * strideAB + 16 * g0;
    const char* pb1 = (const char*)B + (size_t)gb1 * strideAB + 16 * g1;

    const int sread = (lam >> 4) ^ ((lam >> 1) & 3);
    const int abase = wm * 4096 + (lam & 15) * 64 + sread * 16;
    const int bbase = 8192 + wn * 4096 + (lam & 15) * 64 + sread * 16;

    for (int k0 = 0; k0 < K; k0 += 32) {
        __syncthreads();
        const size_t kb = 2 * (size_t)k0;
        GLL(pa0 + kb, smem + w * 1024);
        GLL(pa1 + kb, smem + 4096 + w * 1024);
        GLL(pb0 + kb, smem + 8192 + w * 1024);
        GLL(pb1 + kb, smem + 12288 + w * 1024);
        asm volatile("s_waitcnt vmcnt(0)" ::: "memory");
        __syncthreads();

        bf16x8 aF[4], bF[4];
#pragma unroll
        for (int i = 0; i < 4; ++i) aF[i] = *(const bf16x8*)(smem + abase + 1024 * i);
#pragma unroll
        for (int j = 0; j < 4; ++j) bF[j] = *(const bf16x8*)(smem + bbase + 1024 * j);
#pragma unroll
        for (int i = 0; i < 4; ++i)
#pragma unroll
            for (int j = 0; j < 4; ++j)
                acc[i][j] = __builtin_amdgcn_mfma_f32_16x16x32_bf16(aF[i], bF[j], acc[i][j], 0, 0, 0);
    }

    const int col0 = bn + wn * 64 + (lam & 15);
    const int row0 = bm + wm * 64 + ((lam >> 4) << 2);
#pragma unroll
    for (int j = 0; j < 4; ++j) {
        const int col = col0 + 16 * j;
        if (col >= N) continue;
        const float bv = bias ? biasScale * bias[col] : 0.f;
#pragma unroll
        for (int i = 0; i < 4; ++i) {
#pragma unroll
            for (int r = 0; r < 4; ++r) {
                const int row = row0 + 16 * i + r;
                if (row >= M) continue;
                float v = alpha * acc[i][j][r] + bv;
                if (relu) v = fmaxf(v, 0.f);
                const size_t idx = (size_t)row * N + col;
                if (Cf) Cf[idx] = v;
                if (Ch) Ch[idx] = __float2bfloat16(v);
            }
        }
    }
}

// ---------------------------------------------------------------------------
// Split-bf16 GEMM: C = act((AH+AL)@(BH+BL)^T + bias + res) dropping AL*BL.
// ---------------------------------------------------------------------------
__global__ __launch_bounds__(256) void gemm_bf16_split(
    const bf* __restrict__ AH, const bf* __restrict__ AL,
    const bf* __restrict__ BH, const bf* __restrict__ BL,
    int M, int N, int K, const float* __restrict__ bias,
    const bf* __restrict__ resHi, const bf* __restrict__ resLo,
    float* __restrict__ Cf, bf* __restrict__ Chi, bf* __restrict__ Clo,
    bf* __restrict__ Cb, int relu)
{
    __shared__ __align__(16) char smem[32768];  // AH 0, AL 8192, BH 16384, BL 24576
    const int tid = threadIdx.x;
    const int w   = tid >> 6;
    const int lam = tid & 63;
    const int bm  = blockIdx.y * 128;
    const int bn  = blockIdx.x * 128;
    const int wm  = w >> 1, wn = w & 1;

    f32x4 acc[4][4];
#pragma unroll
    for (int i = 0; i < 4; ++i)
#pragma unroll
        for (int j = 0; j < 4; ++j) acc[i][j] = (f32x4){0.f, 0.f, 0.f, 0.f};

    const int r0s  = w * 16 + (lam >> 2);
    const int slot = lam & 3;
    const int g0   = slot ^ ((r0s >> 1) & 3);
    const int g1   = slot ^ (((r0s + 64) >> 1) & 3);
    const size_t strideAB = (size_t)K * 2;
    long ga0 = bm + r0s;      if (ga0 >= M) ga0 = M - 1;
    long ga1 = bm + r0s + 64; if (ga1 >= M) ga1 = M - 1;
    long gb0 = bn + r0s;      if (gb0 >= N) gb0 = N - 1;
    long gb1 = bn + r0s + 64; if (gb1 >= N) gb1 = N - 1;
    const size_t oa0 = (size_t)ga0 * strideAB + 16 * g0;
    const size_t oa1 = (size_t)ga1 * strideAB + 16 * g1;
    const size_t ob0 = (size_t)gb0 * strideAB + 16 * g0;
    const size_t ob1 = (size_t)gb1 * strideAB + 16 * g1;

    const int sread = (lam >> 4) ^ ((lam >> 1) & 3);
    const int abase = (lam & 15) * 64 + sread * 16;
    const int bbase = (lam & 15) * 64 + sread * 16;

    for (int k0 = 0; k0 < K; k0 += 32) {
        __syncthreads();
        const size_t kb = 2 * (size_t)k0;
        GLL((const char*)AH + oa0 + kb, smem + w * 1024);
        GLL((const char*)AH + oa1 + kb, smem + 4096 + w * 1024);
        GLL((const char*)AL + oa0 + kb, smem + 8192 + w * 1024);
        GLL((const char*)AL + oa1 + kb, smem + 12288 + w * 1024);
        GLL((const char*)BH + ob0 + kb, smem + 16384 + w * 1024);
        GLL((const char*)BH + ob1 + kb, smem + 20480 + w * 1024);
        GLL((const char*)BL + ob0 + kb, smem + 24576 + w * 1024);
        GLL((const char*)BL + ob1 + kb, smem + 28672 + w * 1024);
        asm volatile("s_waitcnt vmcnt(0)" ::: "memory");
        __syncthreads();

        bf16x8 aH[4], aL[4], bH[4], bL[4];
#pragma unroll
        for (int i = 0; i < 4; ++i) {
            aH[i] = *(const bf16x8*)(smem + wm * 4096 + abase + 1024 * i);
            aL[i] = *(const bf16x8*)(smem + 8192 + wm * 4096 + abase + 1024 * i);
        }
#pragma unroll
        for (int j = 0; j < 4; ++j) {
            bH[j] = *(const bf16x8*)(smem + 16384 + wn * 4096 + bbase + 1024 * j);
            bL[j] = *(const bf16x8*)(smem + 24576 + wn * 4096 + bbase + 1024 * j);
        }
#pragma unroll
        for (int i = 0; i < 4; ++i)
#pragma unroll
            for (int j = 0; j < 4; ++j) {
                acc[i][j] = __builtin_amdgcn_mfma_f32_16x16x32_bf16(aH[i], bH[j], acc[i][j], 0, 0, 0);
                acc[i][j] = __builtin_amdgcn_mfma_f32_16x16x32_bf16(aH[i], bL[j], acc[i][j], 0, 0, 0);
                acc[i][j] = __builtin_amdgcn_mfma_f32_16x16x32_bf16(aL[i], bH[j], acc[i][j], 0, 0, 0);
            }
    }

    const int col0 = bn + wn * 64 + (lam & 15);
    const int row0 = bm + wm * 64 + ((lam >> 4) << 2);
#pragma unroll
    for (int j = 0; j < 4; ++j) {
        const int col = col0 + 16 * j;
        if (col >= N) continue;
        const float bv = bias ? bias[col] : 0.f;
#pragma unroll
        for (int i = 0; i < 4; ++i) {
#pragma unroll
            for (int r = 0; r < 4; ++r) {
                const int row = row0 + 16 * i + r;
                if (row >= M) continue;
                float v = acc[i][j][r] + bv;
                const size_t idx = (size_t)row * N + col;
                if (resHi) v += __bfloat162float(resHi[idx]) + __bfloat162float(resLo[idx]);
                if (relu) v = fmaxf(v, 0.f);
                if (Cf) Cf[idx] = v;
                if (Cb) Cb[idx] = __float2bfloat16(v);
                if (Chi) {
                    const float h = __bfloat162float(__float2bfloat16(v));
                    Chi[idx] = __float2bfloat16(v);
                    Clo[idx] = __float2bfloat16(v - h);
                }
            }
        }
    }
}

// ---------------------------------------------------------------------------
// fp32 GEMM (query encoder / predictor; exact path)
// ---------------------------------------------------------------------------
#define TILE 64
#define KT   16
__global__ __launch_bounds__(256) void gemm_bias_act(
    const float* __restrict__ A, const float* __restrict__ B,
    const float* __restrict__ bias, float biasScale,
    const float* __restrict__ resid,
    float* __restrict__ C,
    int M, int N, int K, float alpha, int relu)
{
    __shared__ float As[KT][TILE + 4];
    __shared__ float Bs[KT][TILE + 4];
    const int bm = blockIdx.y * TILE;
    const int bn = blockIdx.x * TILE;
    const int tid = threadIdx.x;
    const int tx = tid & 15;
    const int ty = tid >> 4;
    const int lm = tid >> 2;
    const int lk = (tid & 3) * 4;

    float acc[4][4];
#pragma unroll
    for (int i = 0; i < 4; ++i)
#pragma unroll
        for (int j = 0; j < 4; ++j) acc[i][j] = 0.f;

    for (int k0 = 0; k0 < K; k0 += KT) {
        {
            const int gm = bm + lm;
            float4 v = make_float4(0.f, 0.f, 0.f, 0.f);
            if (gm < M) v = *reinterpret_cast<const float4*>(A + (size_t)gm * K + k0 + lk);
            As[lk + 0][lm] = v.x; As[lk + 1][lm] = v.y;
            As[lk + 2][lm] = v.z; As[lk + 3][lm] = v.w;
            const int gn = bn + lm;
            float4 u = make_float4(0.f, 0.f, 0.f, 0.f);
            if (gn < N) u = *reinterpret_cast<const float4*>(B + (size_t)gn * K + k0 + lk);
            Bs[lk + 0][lm] = u.x; Bs[lk + 1][lm] = u.y;
            Bs[lk + 2][lm] = u.z; Bs[lk + 3][lm] = u.w;
        }
        __syncthreads();
#pragma unroll
        for (int kk = 0; kk < KT; ++kk) {
            float aa[4], bb[4];
#pragma unroll
            for (int i = 0; i < 4; ++i) aa[i] = As[kk][ty * 4 + i];
#pragma unroll
            for (int j = 0; j < 4; ++j) bb[j] = Bs[kk][tx * 4 + j];
#pragma unroll
            for (int i = 0; i < 4; ++i)
#pragma unroll
                for (int j = 0; j < 4; ++j) acc[i][j] += aa[i] * bb[j];
        }
        __syncthreads();
    }
#pragma unroll
    for (int i = 0; i < 4; ++i) {
        const int gm = bm + ty * 4 + i;
        if (gm >= M) continue;
#pragma unroll
        for (int j = 0; j < 4; ++j) {
            const int gn = bn + tx * 4 + j;
            if (gn >= N) continue;
            float v = alpha * acc[i][j];
            if (bias)  v += biasScale * bias[gn];
            if (resid) v += resid[(size_t)gm * N + gn];
            if (relu)  v = fmaxf(v, 0.f);
            C[(size_t)gm * N + gn] = v;
        }
    }
}

// ---------------------------------------------------------------------------
// LayerNorm variants + small helpers
// ---------------------------------------------------------------------------
__global__ void ln_kernel(const float* __restrict__ X, const float* __restrict__ g,
                          const float* __restrict__ b, float* __restrict__ Y, int M)
{
    const int row = blockIdx.x * 4 + (threadIdx.x >> 6);
    const int lane = threadIdx.x & 63;
    if (row >= M) return;
    const float* x = X + (size_t)row * D_MAIN;
    float v[4]; float s = 0.f;
#pragma unroll
    for (int i = 0; i < 4; ++i) { v[i] = x[lane + 64 * i]; s += v[i]; }
#pragma unroll
    for (int o = 32; o > 0; o >>= 1) s += __shfl_xor(s, o);
    const float mu = s * (1.f / D_MAIN);
    float vs = 0.f;
#pragma unroll
    for (int i = 0; i < 4; ++i) { const float d = v[i] - mu; vs += d * d; }
#pragma unroll
    for (int o = 32; o > 0; o >>= 1) vs += __shfl_xor(vs, o);
    const float inv = rsqrtf(vs * (1.f / D_MAIN) + 1e-5f);
    float* y = Y + (size_t)row * D_MAIN;
#pragma unroll
    for (int i = 0; i < 4; ++i) {
        const int d = lane + 64 * i;
        y[d] = (v[i] - mu) * inv * g[d] + b[d];
    }
}

__global__ void ln_split_kernel(const float* __restrict__ X, const float* __restrict__ g,
                                const float* __restrict__ b,
                                bf* __restrict__ Yhi, bf* __restrict__ Ylo, int M)
{
    const int row = blockIdx.x * 4 + (threadIdx.x >> 6);
    const int lane = threadIdx.x & 63;
    if (row >= M) return;
    const float* x = X + (size_t)row * D_MAIN;
    float v[4]; float s = 0.f;
#pragma unroll
    for (int i = 0; i < 4; ++i) { v[i] = x[lane + 64 * i]; s += v[i]; }
#pragma unroll
    for (int o = 32; o > 0; o >>= 1) s += __shfl_xor(s, o);
    const float mu = s * (1.f / D_MAIN);
    float vs = 0.f;
#pragma unroll
    for (int i = 0; i < 4; ++i) { const float d = v[i] - mu; vs += d * d; }
#pragma unroll
    for (int o = 32; o > 0; o >>= 1) vs += __shfl_xor(vs, o);
    const float inv = rsqrtf(vs * (1.f / D_MAIN) + 1e-5f);
#pragma unroll
    for (int i = 0; i < 4; ++i) {
        const int d = lane + 64 * i;
        const float val = (v[i] - mu) * inv * g[d] + b[d];
        const bf h = __float2bfloat16(val);
        Yhi[(size_t)row * D_MAIN + d] = h;
        Ylo[(size_t)row * D_MAIN + d] = __float2bfloat16(val - __bfloat162float(h));
    }
}

__global__ void rowsq_kernel(const float* __restrict__ X, float* __restrict__ sq, int M)
{
    const int row = blockIdx.x * 4 + (threadIdx.x >> 6);
    const int lane = threadIdx.x & 63;
    if (row >= M) return;
    const float* x = X + (size_t)row * D_MAIN;
    float s = 0.f;
#pragma unroll
    for (int i = 0; i < 4; ++i) { const float v = x[lane + 64 * i]; s += v * v; }
#pragma unroll
    for (int o = 32; o > 0; o >>= 1) s += __shfl_xor(s, o);
    if (lane == 0) sq[row] = s;
}

__global__ void head_kernel(const float* __restrict__ X, const float* __restrict__ g,
                            const float* __restrict__ b, const float* __restrict__ W,
                            const float* __restrict__ bh, float* __restrict__ out, int M)
{
    const int row = blockIdx.x * 4 + (threadIdx.x >> 6);
    const int lane = threadIdx.x & 63;
    if (row >= M) return;
    const float* x = X + (size_t)row * D_MAIN;
    float v[4]; float s = 0.f;
#pragma unroll
    for (int i = 0; i < 4; ++i) { v[i] = x[lane + 64 * i]; s += v[i]; }
#pragma unroll
    for (int o = 32; o > 0; o >>= 1) s += __shfl_xor(s, o);
    const float mu = s * (1.f / D_MAIN);
    float vs = 0.f;
#pragma unroll
    for (int i = 0; i < 4; ++i) { const float d = v[i] - mu; vs += d * d; }
#pragma unroll
    for (int o = 32; o > 0; o >>= 1) vs += __shfl_xor(vs, o);
    const float inv = rsqrtf(vs * (1.f / D_MAIN) + 1e-5f);
    float acc = 0.f;
#pragma unroll
    for (int i = 0; i < 4; ++i) {
        const int d = lane + 64 * i;
        float o_ = (v[i] - mu) * inv * g[d] + b[d];
        o_ = fmaxf(o_, 0.f);
        acc += o_ * W[d];
    }
#pragma unroll
    for (int o = 32; o > 0; o >>= 1) acc += __shfl_xor(acc, o);
    if (lane == 0) out[row] = acc + bh[0];
}

__global__ void f2b_kernel(const float* __restrict__ in, bf* __restrict__ out, int n)
{
    const int i = blockIdx.x * 256 + threadIdx.x;
    if (i < n) out[i] = __float2bfloat16(in[i]);
}

__global__ void f2b_split_kernel(const float* __restrict__ in,
                                 bf* __restrict__ hi, bf* __restrict__ lo, int n)
{
    const int i = blockIdx.x * 256 + threadIdx.x;
    if (i < n) {
        const float v = in[i];
        const bf h = __float2bfloat16(v);
        hi[i] = h;
        lo[i] = __float2bfloat16(v - __bfloat162float(h));
    }
}

__global__ void zero_u32(unsigned* __restrict__ p, long n)
{
    for (long i = (long)blockIdx.x * 256 + threadIdx.x; i < n; i += (long)gridDim.x * 256)
        p[i] = 0u;
}

// ---------------------------------------------------------------------------
// Segmented top-K_PRE selection over fp32 scores (full-grid parallel).
// key = float-ordered u32; binning on key>>20 (4096 bins). Semantics match
// the previous monolithic topk exactly -> identical candidate set.
// ---------------------------------------------------------------------------
#define SEGLEN (NTRAIN / 4 / SEG)   // float4s per segment = 3125

__global__ __launch_bounds__(256) void hist_kernel(
    const float* __restrict__ scores, unsigned* __restrict__ histG)
{
    const int ql = blockIdx.y, seg = blockIdx.x, tid = threadIdx.x;
    const float4* row4 = (const float4*)(scores + (size_t)ql * NTRAIN);
    __shared__ unsigned h[4096];
    for (int i = tid; i < 4096; i += 256) h[i] = 0;
    __syncthreads();
    const int base = seg * SEGLEN;
    for (int i = base + tid; i < base + SEGLEN; i += 256) {
        const float4 v = row4[i];
        const float f[4] = {v.x, v.y, v.z, v.w};
#pragma unroll
        for (int c = 0; c < 4; ++c) {
            const unsigned uu = __float_as_uint(f[c]);
            const unsigned key = (uu & 0x80000000u) ? ~uu : (uu | 0x80000000u);
            atomicAdd(&h[key >> 20], 1u);
        }
    }
    __syncthreads();
    unsigned* hg = histG + (size_t)ql * 4096;
    for (int i = tid; i < 4096; i += 256)
        if (h[i]) atomicAdd(&hg[i], h[i]);
}

__global__ __launch_bounds__(256) void bound_kernel(
    const unsigned* __restrict__ histG, unsigned* __restrict__ boundA,
    int* __restrict__ needA, int* __restrict__ cntGA, int* __restrict__ cntEA)
{
    const int ql = blockIdx.x;
    const unsigned* h = histG + (size_t)ql * 4096;
    const int tid = threadIdx.x;
    __shared__ unsigned cs[256];
    unsigned s = 0;
    for (int b = tid * 16; b < tid * 16 + 16; ++b) s += h[b];
    cs[tid] = s;
    __syncthreads();
    if (tid == 0) {
        unsigned cum = 0; int ch = 0;
        for (int t = 255; t >= 0; --t) {
            if (cum + cs[t] >= (unsigned)K_PRE) { ch = t; break; }
            cum += cs[t];
        }
        int bnd = ch * 16;
        for (int bin = ch * 16 + 15; bin >= ch * 16; --bin) {
            const unsigned c = h[bin];
            if (cum + c >= (unsigned)K_PRE) { bnd = bin; break; }
            cum += c;
        }
        boundA[ql] = (unsigned)bnd;
        needA[ql]  = K_PRE - (int)cum;
        cntGA[ql]  = 0;
        cntEA[ql]  = 0;
    }
}

__global__ __launch_bounds__(256) void gather_kernel(
    const float* __restrict__ scores, const unsigned* __restrict__ boundA,
    int* __restrict__ cntGA, int* __restrict__ cntEA,
    int* __restrict__ idx128, int* __restrict__ eqI, unsigned* __restrict__ eqK,
    int q0)
{
    const int ql = blockIdx.y, seg = blockIdx.x, tid = threadIdx.x;
    const float4* row4 = (const float4*)(scores + (size_t)ql * NTRAIN);
    const unsigned bnd = boundA[ql];
    const int q = q0 + ql;
    const int base = seg * SEGLEN;
    for (int i = base + tid; i < base + SEGLEN; i += 256) {
        const float4 v = row4[i];
        const float f[4] = {v.x, v.y, v.z, v.w};
#pragma unroll
        for (int c = 0; c < 4; ++c) {
            const unsigned uu = __float_as_uint(f[c]);
            const unsigned key = (uu & 0x80000000u) ? ~uu : (uu | 0x80000000u);
            const unsigned b12 = key >> 20;
            if (b12 > bnd) {
                const int p = atomicAdd(&cntGA[ql], 1);
                if (p < K_PRE) idx128[(size_t)q * K_PRE + p] = 4 * i + c;
            } else if (b12 == bnd) {
                const int p = atomicAdd(&cntEA[ql], 1);
                if (p < EQCAP) {
                    eqI[(size_t)ql * EQCAP + p] = 4 * i + c;
                    eqK[(size_t)ql * EQCAP + p] = key;
                }
            }
        }
    }
}

__global__ __launch_bounds__(256) void refine_kernel(
    int* __restrict__ eqIa, unsigned* __restrict__ eqKa,
    int* __restrict__ eqIb, unsigned* __restrict__ eqKb,
    const int* __restrict__ cntEA, const int* __restrict__ needA,
    const int* __restrict__ cntGA, int* __restrict__ idx128, int q0)
{
    const int ql = blockIdx.x;
    const int q = q0 + ql;
    const int tid = threadIdx.x;
    __shared__ unsigned hist2[256];
    __shared__ int sh_bnd, sh_need, sh_cntE, sh_cntG;

    int E = cntEA[ql]; if (E > EQCAP) E = EQCAP;
    int need = needA[ql];
    if (tid == 0) sh_cntG = cntGA[ql];
    __syncthreads();

    int* iA = eqIa + (size_t)ql * EQCAP;  unsigned* kA = eqKa + (size_t)ql * EQCAP;
    int* iB = eqIb + (size_t)ql * EQCAP;  unsigned* kB = eqKb + (size_t)ql * EQCAP;
    int curA = 1;

    for (int lvl = 0; lvl < 3 && need > 0; ++lvl) {
        const int sh = (lvl == 0) ? 12 : (lvl == 1) ? 4 : 0;
        const unsigned msk = (lvl == 2) ? 15u : 255u;
        const int nb = (lvl == 2) ? 16 : 256;
        for (int bin = tid; bin < nb; bin += 256) hist2[bin] = 0;
        if (tid == 0) sh_cntE = 0;
        __syncthreads();
        const int* ci = curA ? iA : iB;
        const unsigned* ki = curA ? kA : kB;
        int* io = curA ? iB : iA;
        unsigned* ko = curA ? kB : kA;
        for (int e = tid; e < E; e += 256) atomicAdd(&hist2[(ki[e] >> sh) & msk], 1u);
        __syncthreads();
        if (tid == 0) {
            unsigned cum = 0; int b2 = 0;
            for (int bin = nb - 1; bin >= 0; --bin) {
                const unsigned c = hist2[bin];
                if (cum + c >= (unsigned)need) { b2 = bin; break; }
                cum += c;
            }
            sh_bnd = b2; sh_need = need - (int)cum;
        }
        __syncthreads();
        const unsigned b2 = (unsigned)sh_bnd;
        for (int e = tid; e < E; e += 256) {
            const unsigned f = (ki[e] >> sh) & msk;
            if (f > b2) {
                const int p = atomicAdd(&sh_cntG, 1);
                if (p < K_PRE) idx128[(size_t)q * K_PRE + p] = ci[e];
            } else if (f == b2) {
                const int p = atomicAdd(&sh_cntE, 1);
                if (p < EQCAP) { io[p] = ci[e]; ko[p] = ki[e]; }
            }
        }
        __syncthreads();
        E = sh_cntE < EQCAP ? sh_cntE : EQCAP;
        need = sh_need;
        curA ^= 1;
        __syncthreads();
    }

    if (tid == 0) {
        int cg = sh_cntG;
        if (need > 0) {
            const int* ci = curA ? iA : iB;
            int last = -1;
            for (int t = 0; t < need; ++t) {
                int best = 0x7fffffff;
                for (int e = 0; e < E; ++e) {
                    const int v = ci[e];
                    if (v > last && v < best) best = v;
                }
                if (best != 0x7fffffff) {
                    if (cg < K_PRE) idx128[(size_t)q * K_PRE + cg] = best;
                    ++cg; last = best;
                }
            }
        }
        int tot = cg < K_PRE ? cg : K_PRE;
        if (tot == 0) { idx128[(size_t)q * K_PRE] = 0; tot = 1; }
        const int fill = idx128[(size_t)q * K_PRE];
        for (int t = tot; t < K_PRE; ++t) idx128[(size_t)q * K_PRE + t] = fill;
    }
}

// ---------------------------------------------------------------------------
// Exact re-rank: fp32 d2 over 128 candidates, top-96 with (d2, idx) tie rule,
// output idx sorted ascending + exact sims = -d2. One block per query.
// ---------------------------------------------------------------------------
__global__ __launch_bounds__(256) void rerank_kernel(
    const float* __restrict__ k_q, const float* __restrict__ ck,
    const int* __restrict__ idx128, int* __restrict__ idx96,
    float* __restrict__ sims96)
{
    const int q = blockIdx.x;
    const int tid = threadIdx.x;
    const int w = tid >> 6, lam = tid & 63;
    __shared__ float kq[D_MAIN];
    __shared__ unsigned long long keys[K_PRE];
    kq[tid] = k_q[(size_t)q * D_MAIN + tid];
    __syncthreads();

    for (int c = w * 32; c < w * 32 + 32; ++c) {
        const int j = idx128[(size_t)q * K_PRE + c];
        const float4 cv = *(const float4*)(ck + (size_t)j * D_MAIN + lam * 4);
        const float d0 = kq[lam * 4 + 0] - cv.x;
        const float d1 = kq[lam * 4 + 1] - cv.y;
        const float d2_ = kq[lam * 4 + 2] - cv.z;
        const float d3 = kq[lam * 4 + 3] - cv.w;
        float s = d0 * d0 + d1 * d1 + d2_ * d2_ + d3 * d3;
#pragma unroll
        for (int o = 32; o > 0; o >>= 1) s += __shfl_xor(s, o);
        if (lam == 0)
            keys[c] = ((unsigned long long)__float_as_uint(s) << 32) | (unsigned)j;
    }
    __syncthreads();

    for (int k = 2; k <= K_PRE; k <<= 1) {
        for (int j = k >> 1; j > 0; j >>= 1) {
            if (tid < K_PRE) {
                const int ixj = tid ^ j;
                if (ixj > tid) {
                    const bool up = ((tid & k) == 0);
                    const unsigned long long a = keys[tid], b2 = keys[ixj];
                    if ((a > b2) == up) { keys[tid] = b2; keys[ixj] = a; }
                }
            }
            __syncthreads();
        }
    }
    unsigned long long k2 = ~0ull;
    if (tid < CTX) k2 = (keys[tid] << 32) | (keys[tid] >> 32);
    __syncthreads();
    if (tid < K_PRE) keys[tid] = k2;
    __syncthreads();
    for (int k = 2; k <= K_PRE; k <<= 1) {
        for (int j = k >> 1; j > 0; j >>= 1) {
            if (tid < K_PRE) {
                const int ixj = tid ^ j;
                if (ixj > tid) {
                    const bool up = ((tid & k) == 0);
                    const unsigned long long a = keys[tid], b2 = keys[ixj];
                    if ((a > b2) == up) { keys[tid] = b2; keys[ixj] = a; }
                }
            }
            __syncthreads();
        }
    }
    if (tid < CTX) {
        idx96[(size_t)q * CTX + tid] = (int)(keys[tid] >> 32);
        sims96[(size_t)q * CTX + tid] = -__uint_as_float((unsigned)(keys[tid] & 0xffffffffu));
    }
}

__global__ void gather_diff(const float* __restrict__ k_q, const float* __restrict__ ck,
                            const int* __restrict__ idxA, int q0, bf* __restrict__ diff)
{
    const int r = blockIdx.x;
    const int q = q0 + r / CTX;
    const int c = r % CTX;
    const int j = idxA[(size_t)q * CTX + c];
    const int d = threadIdx.x;
    const float df = k_q[(size_t)q * D_MAIN + d] - ck[(size_t)j * D_MAIN + d];
    diff[(size_t)r * D_MAIN + d] = __float2bfloat16(df);
}

__global__ void combine_kernel(const float* __restrict__ sscA, const int* __restrict__ idxA,
                               const float* __restrict__ ytr, const float* __restrict__ w_lab,
                               const float* __restrict__ b_lab, const float* __restrict__ vv,
                               float* __restrict__ x_q, int q0)
{
    const int q = q0 + blockIdx.x;
    __shared__ float pr[CTX];
    __shared__ float sh_ybar;
    const int tid = threadIdx.x;
    if (tid == 0) {
        float mx = -1e30f;
        for (int c = 0; c < CTX; ++c) mx = fmaxf(mx, sscA[(size_t)q * CTX + c]);
        float sum = 0.f;
        for (int c = 0; c < CTX; ++c) {
            const float e = __expf(sscA[(size_t)q * CTX + c] - mx);
            pr[c] = e; sum += e;
        }
        const float inv = 1.f / sum;
        float yb = 0.f;
        for (int c = 0; c < CTX; ++c) {
            pr[c] *= inv;
            yb += pr[c] * ytr[idxA[(size_t)q * CTX + c]];
        }
        sh_ybar = yb;
    }
    __syncthreads();
    const int d = tid;
    float acc = 0.f;
    const float* vq = vv + (size_t)blockIdx.x * CTX * D_MAIN;
    for (int c = 0; c < CTX; ++c) acc += pr[c] * vq[(size_t)c * D_MAIN + d];
    x_q[(size_t)q * D_MAIN + d] += acc + sh_ybar * w_lab[d] + b_lab[d];
}

// ---------------------------------------------------------------------------
extern "C" void kernel_launch(void* const* d_in, const int* in_sizes, int n_in,
                              void* d_out, int out_size, void* d_ws, size_t ws_size,
                              hipStream_t stream)
{
    const float* X      = (const float*)d_in[0];
    const float* Xtr    = (const float*)d_in[1];
    const float* ytr    = (const float*)d_in[2];
    const float* W_in   = (const float*)d_in[3];
    const float* b_in   = (const float*)d_in[4];
    const float* W0a    = (const float*)d_in[5];
    const float* b0a    = (const float*)d_in[6];
    const float* W0b    = (const float*)d_in[7];
    const float* b0b    = (const float*)d_in[8];
    const float* g_mix  = (const float*)d_in[9];
    const float* be_mix = (const float*)d_in[10];
    const float* W_k    = (const float*)d_in[11];
    const float* b_k    = (const float*)d_in[12];
    const float* w_lab  = (const float*)d_in[13];
    const float* b_lab  = (const float*)d_in[14];
    const float* W_t1   = (const float*)d_in[15];
    const float* b_t1   = (const float*)d_in[16];
    const float* W_t2   = (const float*)d_in[17];
    const float* g_p    = (const float*)d_in[18];
    const float* be_p   = (const float*)d_in[19];
    const float* W1a    = (const float*)d_in[20];
    const float* b1a    = (const float*)d_in[21];
    const float* W1b    = (const float*)d_in[22];
    const float* b1b    = (const float*)d_in[23];
    const float* g_h    = (const float*)d_in[24];
    const float* be_h   = (const float*)d_in[25];
    const float* W_h    = (const float*)d_in[26];
    const float* b_h    = (const float*)d_in[27];
    float* out = (float*)d_out;

    char* ws = (char*)d_ws;
    size_t off = 0;
    auto alloc = [&](size_t bytes) -> void* {
        void* p = ws + off;
        off += (bytes + 255) & ~(size_t)255;
        return p;
    };
    float* ck    = (float*)alloc((size_t)NTRAIN * D_MAIN * 4);
    bf*    ckh   = (bf*)   alloc((size_t)NTRAIN * D_MAIN * 2);
    float* sqc   = (float*)alloc((size_t)NTRAIN * 4);
    bf*    XtrH  = (bf*)   alloc((size_t)NTRAIN * D_IN * 2);
    bf*    XtrL  = (bf*)   alloc((size_t)NTRAIN * D_IN * 2);
    bf*    WinH  = (bf*)   alloc((size_t)D_MAIN * D_IN * 2);
    bf*    WinL  = (bf*)   alloc((size_t)D_MAIN * D_IN * 2);
    bf*    W0aH  = (bf*)   alloc((size_t)D_BLOCK * D_MAIN * 2);
    bf*    W0aL  = (bf*)   alloc((size_t)D_BLOCK * D_MAIN * 2);
    bf*    W0bH  = (bf*)   alloc((size_t)D_MAIN * D_BLOCK * 2);
    bf*    W0bL  = (bf*)   alloc((size_t)D_MAIN * D_BLOCK * 2);
    bf*    WkH   = (bf*)   alloc((size_t)D_MAIN * D_MAIN * 2);
    bf*    WkL   = (bf*)   alloc((size_t)D_MAIN * D_MAIN * 2);
    bf*    Wt1b  = (bf*)   alloc((size_t)D_BLOCK * D_MAIN * 2);
    bf*    Wt2b  = (bf*)   alloc((size_t)D_MAIN * D_BLOCK * 2);
    float* x_q   = (float*)alloc((size_t)NQ * D_MAIN * 4);
    float* h_q   = (float*)alloc((size_t)NQ * D_MAIN * 4);
    float* t_q   = (float*)alloc((size_t)NQ * D_BLOCK * 4);
    float* ln_q  = (float*)alloc((size_t)NQ * D_MAIN * 4);
    float* k_q   = (float*)alloc((size_t)NQ * D_MAIN * 4);
    bf*    k_qb  = (bf*)   alloc((size_t)NQ * D_MAIN * 2);
    int*   idx128 = (int*) alloc((size_t)NQ * K_PRE * 4);
    int*   idxA  = (int*)  alloc((size_t)NQ * CTX * 4);
    float* sscA  = (float*)alloc((size_t)NQ * CTX * 4);

    const size_t bigOff = off;
    const size_t bigBytes = (ws_size > bigOff) ? (ws_size - bigOff) : 0;
    char* big = ws + bigOff;

    auto f2b = [&](const float* in, bf* o, int n) {
        f2b_kernel<<<(n + 255) / 256, 256, 0, stream>>>(in, o, n);
    };
    auto f2bs = [&](const float* in, bf* hi, bf* lo, int n) {
        f2b_split_kernel<<<(n + 255) / 256, 256, 0, stream>>>(in, hi, lo, n);
    };

    f2bs(W_in, WinH, WinL, D_MAIN * D_IN);
    f2bs(W0a,  W0aH, W0aL, D_BLOCK * D_MAIN);
    f2bs(W0b,  W0bH, W0bL, D_MAIN * D_BLOCK);
    f2bs(W_k,  WkH,  WkL,  D_MAIN * D_MAIN);
    f2bs(Xtr,  XtrH, XtrL, NTRAIN * D_IN);
    f2b(W_t1, Wt1b, D_BLOCK * D_MAIN);
    f2b(W_t2, Wt2b, D_MAIN * D_BLOCK);

    // ---------------- encode queries (fp32 exact) ----------------
    {
        dim3 g1((D_MAIN + TILE - 1) / TILE, (NQ + TILE - 1) / TILE);
        gemm_bias_act<<<g1, 256, 0, stream>>>(X, W_in, b_in, 1.f, nullptr, h_q, NQ, D_MAIN, D_IN, 1.f, 0);
        dim3 g2((D_BLOCK + TILE - 1) / TILE, (NQ + TILE - 1) / TILE);
        gemm_bias_act<<<g2, 256, 0, stream>>>(h_q, W0a, b0a, 1.f, nullptr, t_q, NQ, D_BLOCK, D_MAIN, 1.f, 1);
        gemm_bias_act<<<g1, 256, 0, stream>>>(t_q, W0b, b0b, 1.f, h_q, x_q, NQ, D_MAIN, D_BLOCK, 1.f, 0);
        ln_kernel<<<(NQ + 3) / 4, 256, 0, stream>>>(x_q, g_mix, be_mix, ln_q, NQ);
        gemm_bias_act<<<g1, 256, 0, stream>>>(ln_q, W_k, b_k, 1.f, nullptr, k_q, NQ, D_MAIN, D_MAIN, 1.f, 0);
        f2b_kernel<<<(NQ * D_MAIN + 255) / 256, 256, 0, stream>>>(k_q, k_qb, NQ * D_MAIN);
    }

    // ---------------- encode train (split-bf16 MFMA, chunked) ----------------
    {
        long Rmax = (long)(bigBytes / 5120);
        int R = (int)(Rmax < 50048 ? Rmax : 50048);
        R &= ~127;
        if (R < 128) R = 128;
        bf*    hH  = (bf*)big;
        bf*    hL  = (bf*)(big + (size_t)R * 512);
        bf*    tH  = (bf*)(big + (size_t)R * 1024);
        bf*    tL  = (bf*)(big + (size_t)R * 2048);
        float* x_f = (float*)(big + (size_t)R * 3072);
        bf*    lnH = (bf*)(big + (size_t)R * 4096);
        bf*    lnL = (bf*)(big + (size_t)R * 4608);
        for (int r0 = 0; r0 < NTRAIN; r0 += R) {
            const int Rc = (NTRAIN - r0 < R) ? (NTRAIN - r0) : R;
            dim3 gA(2, (Rc + 127) / 128);
            dim3 gB(4, (Rc + 127) / 128);
            gemm_bf16_split<<<gA, 256, 0, stream>>>(XtrH + (size_t)r0 * D_IN, XtrL + (size_t)r0 * D_IN,
                WinH, WinL, Rc, D_MAIN, D_IN, b_in, nullptr, nullptr,
                nullptr, hH, hL, nullptr, 0);
            gemm_bf16_split<<<gB, 256, 0, stream>>>(hH, hL, W0aH, W0aL, Rc, D_BLOCK, D_MAIN,
                b0a, nullptr, nullptr, nullptr, tH, tL, nullptr, 1);
            gemm_bf16_split<<<gA, 256, 0, stream>>>(tH, tL, W0bH, W0bL, Rc, D_MAIN, D_BLOCK,
                b0b, hH, hL, x_f, nullptr, nullptr, nullptr, 0);
            ln_split_kernel<<<(Rc + 3) / 4, 256, 0, stream>>>(x_f, g_mix, be_mix, lnH, lnL, Rc);
            gemm_bf16_split<<<gA, 256, 0, stream>>>(lnH, lnL, WkH, WkL, Rc, D_MAIN, D_MAIN,
                b_k, nullptr, nullptr, ck + (size_t)r0 * D_MAIN, nullptr, nullptr,
                ckh + (size_t)r0 * D_MAIN, 0);
        }
    }
    rowsq_kernel<<<(NTRAIN + 3) / 4, 256, 0, stream>>>(ck, sqc, NTRAIN);

    // ---------------- phase A: scores (bf16) + segmented preselect-128 ----------------
    {
        // per-query: scores 400000 + hist 16384 + bound/need/cntG/cntE 16 + eq 4*EQCAP*4
        const size_t perQ = (size_t)NTRAIN * 4 + 4096 * 4 + 16 + (size_t)EQCAP * 16;
        long Qmax = (long)(bigBytes / perQ);
        int Q = (int)(Qmax < NQ ? Qmax : NQ);
        if (Q < 1) Q = 1;
        float*    scores = (float*)big;
        unsigned* histG  = (unsigned*)(big + (size_t)Q * NTRAIN * 4);
        unsigned* boundA = (unsigned*)((char*)histG + (size_t)Q * 4096 * 4);
        int*      needA  = (int*)((char*)boundA + (size_t)Q * 4);
        int*      cntGA  = (int*)((char*)needA + (size_t)Q * 4);
        int*      cntEA  = (int*)((char*)cntGA + (size_t)Q * 4);
        int*      eqIa   = (int*)((char*)cntEA + (size_t)Q * 4);
        unsigned* eqKa   = (unsigned*)((char*)eqIa + (size_t)Q * EQCAP * 4);
        int*      eqIb   = (int*)((char*)eqKa + (size_t)Q * EQCAP * 4);
        unsigned* eqKb   = (unsigned*)((char*)eqIb + (size_t)Q * EQCAP * 4);
        for (int q0 = 0; q0 < NQ; q0 += Q) {
            const int Qc = (NQ - q0 < Q) ? (NQ - q0) : Q;
            dim3 gs((NTRAIN + 127) / 128, (Qc + 127) / 128);
            gemm_bf16<<<gs, 256, 0, stream>>>(k_qb + (size_t)q0 * D_MAIN, ckh, Qc, NTRAIN, D_MAIN,
                2.f, sqc, -1.f, scores, nullptr, 0);
            zero_u32<<<2048, 256, 0, stream>>>(histG, (long)Qc * 4096);
            hist_kernel<<<dim3(SEG, Qc), 256, 0, stream>>>(scores, histG);
            bound_kernel<<<Qc, 256, 0, stream>>>(histG, boundA, needA, cntGA, cntEA);
            gather_kernel<<<dim3(SEG, Qc), 256, 0, stream>>>(scores, boundA, cntGA, cntEA,
                idx128, eqIa, eqKa, q0);
            refine_kernel<<<Qc, 256, 0, stream>>>(eqIa, eqKa, eqIb, eqKb,
                cntEA, needA, cntGA, idx128, q0);
        }
    }

    // ---------------- phase B: exact re-rank to top-96 ----------------
    rerank_kernel<<<NQ, 256, 0, stream>>>(k_q, ck, idx128, idxA, sscA);

    // ---------------- phase C: values MLP + combine (chunked) ----------------
    {
        const size_t perQ = (size_t)CTX * (D_MAIN * 2 + D_BLOCK * 2 + D_MAIN * 4);
        long Qmax = (long)(bigBytes / perQ);
        int Q = (int)(Qmax < NQ ? Qmax : NQ);
        if (Q < 1) Q = 1;
        for (int q0 = 0; q0 < NQ; q0 += Q) {
            const int Qc = (NQ - q0 < Q) ? (NQ - q0) : Q;
            bf*    diff = (bf*)big;
            bf*    tt   = (bf*)(big + (size_t)Qc * CTX * D_MAIN * 2);
            float* vv   = (float*)(big + (size_t)Qc * CTX * D_MAIN * 2 + (size_t)Qc * CTX * D_BLOCK * 2);
            gather_diff<<<Qc * CTX, 256, 0, stream>>>(k_q, ck, idxA, q0, diff);
            dim3 g1((D_BLOCK + 127) / 128, (Qc * CTX + 127) / 128);
            gemm_bf16<<<g1, 256, 0, stream>>>(diff, Wt1b, Qc * CTX, D_BLOCK, D_MAIN,
                1.f, b_t1, 1.f, nullptr, tt, 1);
            dim3 g2((D_MAIN + 127) / 128, (Qc * CTX + 127) / 128);
            gemm_bf16<<<g2, 256, 0, stream>>>(tt, Wt2b, Qc * CTX, D_MAIN, D_BLOCK,
                1.f, nullptr, 0.f, vv, nullptr, 0);
            combine_kernel<<<Qc, 256, 0, stream>>>(sscA, idxA, ytr, w_lab, b_lab, vv, x_q, q0);
        }
    }

    // ---------------- predictor + head (fp32 exact) ----------------
    {
        dim3 g1((D_MAIN + TILE - 1) / TILE, (NQ + TILE - 1) / TILE);
        dim3 g2((D_BLOCK + TILE - 1) / TILE, (NQ + TILE - 1) / TILE);
        ln_kernel<<<(NQ + 3) / 4, 256, 0, stream>>>(x_q, g_p, be_p, ln_q, NQ);
        gemm_bias_act<<<g2, 256, 0, stream>>>(ln_q, W1a, b1a, 1.f, nullptr, t_q, NQ, D_BLOCK, D_MAIN, 1.f, 1);
        gemm_bias_act<<<g1, 256, 0, stream>>>(t_q, W1b, b1b, 1.f, x_q, x_q, NQ, D_MAIN, D_BLOCK, 1.f, 0);
        head_kernel<<<(NQ + 3) / 4, 256, 0, stream>>>(x_q, g_h, be_h, W_h, b_h, out, NQ);
    }
}